// Round 13
// baseline (1247.494 us; speedup 1.0000x reference)
//
#include <hip/hip_runtime.h>

#define MTB 65536   // T*B rows

typedef unsigned int uint;
typedef unsigned short ushort;

typedef _Float16 h8 __attribute__((ext_vector_type(8)));   // 8 fp16 (4 VGPR)
typedef __attribute__((ext_vector_type(4))) float f4;      // mfma accumulator

enum { E_BIAS=1, E_RELU=2, E_ACC=4, E_RES=8, E_PE=16, E_MASKA=32 };

__device__ __forceinline__ float ldsc(const float* p) { return *p; }
__device__ __forceinline__ float ldsc(const _Float16* p) { return (float)*p; }

__device__ __forceinline__ h8 uint4_to_h8(uint4 u) { return __builtin_bit_cast(h8, u); }

// ---------------------------------------------------------------------------
// fp16 MFMA GEMM: C = A @ W^T (+epilogue), 128x128 tile, BK=32.
// (unchanged from rounds 8-12)
// ---------------------------------------------------------------------------
template<int EPI, int AMODE, int BMODE, typename CT, int CPL, typename RT, int RPL>
__global__ __launch_bounds__(256) void gemm_h(
    int M, int N, int K,
    const void* __restrict__ Ap, const void* __restrict__ Ap2, int lda, long batchA,
    const void* __restrict__ Bp, int ldw, long batchW,
    CT* __restrict__ C, long cplane, int ldc, long batchC,
    const float* __restrict__ bias,
    const RT* __restrict__ res, const RT* __restrict__ resLo,
    const float* __restrict__ pe,
    const int* __restrict__ seqlen)
{
    __shared__ _Float16 Ah[128][40];
    __shared__ _Float16 Al[(AMODE==3)?128:1][40];
    __shared__ _Float16 Bh[128][40];
    __shared__ _Float16 Bl[(BMODE==0)?128:1][40];

    const int z = blockIdx.z;
    C += (size_t)z * batchC;
    const float*    Af  = (const float*)Ap + (AMODE==0 ? (size_t)z*batchA : 0);
    const _Float16* Ahp = (const _Float16*)Ap + ((AMODE==2||AMODE==3) ? (size_t)z*batchA : 0);
    const _Float16* Alp = (const _Float16*)Ap2 + (AMODE==3 ? (size_t)z*batchA : 0);
    const float*    Bf  = (const float*)Bp + (BMODE!=2 ? (size_t)z*batchW : 0);
    const _Float16* Bhp = (const _Float16*)Bp;

    const int m0 = blockIdx.y * 128, n0 = blockIdx.x * 128;
    const int tid = threadIdx.x;
    const int lane = tid & 63, wid = tid >> 6;
    const int wr = wid >> 1, wc = wid & 1;

    f4 acc[4][4];
    {
        f4 zr = {0.f, 0.f, 0.f, 0.f};
        #pragma unroll
        for (int i = 0; i < 4; i++)
            #pragma unroll
            for (int j = 0; j < 4; j++) acc[i][j] = zr;
    }

    for (int k0 = 0; k0 < K; k0 += 32) {
        __syncthreads();
        // ---- stage A ----
        if (AMODE == 0 || (AMODE == 4 && k0 < 256)) {
            #pragma unroll
            for (int i = 0; i < 4; i++) {
                const int row = i*32 + (tid>>3);
                const int cg  = (tid&7)<<2;
                const int m = m0 + row;
                float4 v; v.x=0.f; v.y=0.f; v.z=0.f; v.w=0.f;
                bool ok = true;
                if (EPI & E_MASKA) ok = ((m>>8) < seqlen[m&255]);
                if (ok) v = *(const float4*)(Af + (size_t)m*lda + k0 + cg);
                Ah[row][cg+0] = (_Float16)v.x;
                Ah[row][cg+1] = (_Float16)v.y;
                Ah[row][cg+2] = (_Float16)v.z;
                Ah[row][cg+3] = (_Float16)v.w;
            }
        } else if (AMODE == 4) {
            const _Float16* Ar = (const _Float16*)Ap2;
            const int row = tid >> 1;
            const int cg  = (tid & 1) << 4;
            const size_t off = (size_t)(m0 + row) * 256 + (k0 - 256) + cg;
            *(uint4*)&Ah[row][cg]     = *(const uint4*)(Ar + off);
            *(uint4*)&Ah[row][cg + 8] = *(const uint4*)(Ar + off + 8);
        } else {
            const int row = tid >> 1;
            const int cg  = (tid & 1) << 4;
            const size_t off = (size_t)(m0 + row) * lda + k0 + cg;
            *(uint4*)&Ah[row][cg]     = *(const uint4*)(Ahp + off);
            *(uint4*)&Ah[row][cg + 8] = *(const uint4*)(Ahp + off + 8);
            if (AMODE == 3) {
                *(uint4*)&Al[row][cg]     = *(const uint4*)(Alp + off);
                *(uint4*)&Al[row][cg + 8] = *(const uint4*)(Alp + off + 8);
            }
        }
        // ---- stage B ----
        if (BMODE == 2) {
            const int row = tid >> 1;
            const int cg  = (tid & 1) << 4;
            const size_t off = (size_t)(n0 + row) * ldw + k0 + cg;
            *(uint4*)&Bh[row][cg]     = *(const uint4*)(Bhp + off);
            *(uint4*)&Bh[row][cg + 8] = *(const uint4*)(Bhp + off + 8);
        } else if (BMODE == 0) {
            #pragma unroll
            for (int i = 0; i < 4; i++) {
                const int row = i*32 + (tid>>3);
                const int cg  = (tid&7)<<2;
                float4 v = *(const float4*)(Bf + (size_t)(n0+row)*ldw + k0 + cg);
                _Float16 h0 = (_Float16)v.x, h1 = (_Float16)v.y,
                         h2 = (_Float16)v.z, h3 = (_Float16)v.w;
                Bh[row][cg+0]=h0; Bl[row][cg+0]=(_Float16)(v.x-(float)h0);
                Bh[row][cg+1]=h1; Bl[row][cg+1]=(_Float16)(v.y-(float)h1);
                Bh[row][cg+2]=h2; Bl[row][cg+2]=(_Float16)(v.z-(float)h2);
                Bh[row][cg+3]=h3; Bl[row][cg+3]=(_Float16)(v.w-(float)h3);
            }
        } else {  // BMODE == 1 : W f32 [K,N], transpose + cvt
            #pragma unroll
            for (int i = 0; i < 4; i++) {
                const int kr = i*8 + (tid>>5);
                const int ng = (tid&31)<<2;
                float4 v = *(const float4*)(Bf + (size_t)(k0+kr)*ldw + n0 + ng);
                Bh[ng+0][kr] = (_Float16)v.x;
                Bh[ng+1][kr] = (_Float16)v.y;
                Bh[ng+2][kr] = (_Float16)v.z;
                Bh[ng+3][kr] = (_Float16)v.w;
            }
        }
        __syncthreads();
        // ---- fragments + MFMA ----
        const int lr = lane & 15, lk = (lane>>4)<<3;
        h8 ah[4], bh[4];
        #pragma unroll
        for (int i = 0; i < 4; i++) {
            ah[i] = *(const h8*)&Ah[wr*64 + i*16 + lr][lk];
            bh[i] = *(const h8*)&Bh[wc*64 + i*16 + lr][lk];
        }
        #pragma unroll
        for (int mi = 0; mi < 4; mi++)
            #pragma unroll
            for (int ni = 0; ni < 4; ni++)
                acc[mi][ni] = __builtin_amdgcn_mfma_f32_16x16x32_f16(ah[mi], bh[ni], acc[mi][ni], 0, 0, 0);
        if (AMODE == 3) {
            h8 al[4], bl[4];
            #pragma unroll
            for (int i = 0; i < 4; i++) {
                al[i] = *(const h8*)&Al[wr*64 + i*16 + lr][lk];
                bl[i] = *(const h8*)&Bl[wc*64 + i*16 + lr][lk];
            }
            #pragma unroll
            for (int mi = 0; mi < 4; mi++)
                #pragma unroll
                for (int ni = 0; ni < 4; ni++) {
                    acc[mi][ni] = __builtin_amdgcn_mfma_f32_16x16x32_f16(ah[mi], bl[ni], acc[mi][ni], 0, 0, 0);
                    acc[mi][ni] = __builtin_amdgcn_mfma_f32_16x16x32_f16(al[mi], bh[ni], acc[mi][ni], 0, 0, 0);
                }
        }
    }
    // ---- epilogue: C row = 4*(lane>>4)+reg, col = lane&15 ----
    const int colb = n0 + wc*64;
    const int rowb = m0 + wr*64;
    #pragma unroll
    for (int ni = 0; ni < 4; ni++) {
        const int col = colb + ni*16 + (lane & 15);
        float bv = (EPI & E_BIAS) ? bias[col] : 0.f;
        #pragma unroll
        for (int mi = 0; mi < 4; mi++) {
            const int r0 = rowb + mi*16 + ((lane>>4)<<2);
            #pragma unroll
            for (int j = 0; j < 4; j++) {
                const int row = r0 + j;
                const size_t idx = (size_t)row*ldc + col;
                float v = acc[mi][ni][j] + bv;
                if (EPI & E_PE)  v += pe[((row & 255) << 8) + col];
                if (EPI & E_RES) {
                    v += ldsc(res + idx);
                    if (RPL) v += ldsc(resLo + idx);
                }
                CT* cp = C + idx;
                if (EPI & E_ACC) v += ldsc((const CT*)cp);
                if (EPI & E_RELU) v = fmaxf(v, 0.f);
                if (CPL) {
                    _Float16 hh = (_Float16)v;
                    *(_Float16*)cp = hh;
                    *((_Float16*)cp + cplane) = (_Float16)(v - (float)hh);
                } else if (sizeof(CT) == 2) {
                    *(_Float16*)cp = (_Float16)v;
                } else {
                    *(float*)cp = v;
                }
            }
        }
    }
}

// ---------------------------------------------------------------------------
// Fused FF v6: res2 = h1 + relu(h1 @ W1^T + b1) @ W2^T + b2, 64 h-rows/block.
// DFF chunks of 64; full W1/W2 chunk staged at once into a shared LDS union;
// 4 barriers per chunk (128 total); 32 MFMAs/wave per phase; T14 prefetch.
// WB union: W1 view [64][264] (b128), W2 view [256][68] (b64). zt [64][136].
// ---------------------------------------------------------------------------
__global__ __launch_bounds__(256) void ff_kernel(
    const _Float16* __restrict__ h1,    // [65536][256] fp16
    const _Float16* __restrict__ W1p,   // [2048][256] fp16
    const _Float16* __restrict__ W2p,   // [256][2048] fp16
    const float* __restrict__ b1,
    const float* __restrict__ b2,
    float* __restrict__ res2)           // [65536][256] f32
{
    __shared__ _Float16 WB[17408];      // 34.8 KB union
    __shared__ _Float16 zt[64][136];    // 17.4 KB
    const int m0 = blockIdx.x * 64;
    const int tid = threadIdx.x;
    const int lane = tid & 63, wid = tid >> 6;
    const int wr = wid >> 1, wc = wid & 1;
    const int lr = lane & 15, lg = lane >> 4;
    const int lk = lg << 3;
    const int l4 = lg << 2;
    const int prow = tid >> 2;          // W1 stage row 0..63
    const int pcol = (tid & 3) << 6;    // W1 stage col base (0/64/128/192)

    // h1 A-fragments in registers (GEMM1): rows m0+wr*32+mi*16+lr, k=ks*32+lk
    h8 af[2][8];
    #pragma unroll
    for (int mi = 0; mi < 2; mi++)
        #pragma unroll
        for (int ks = 0; ks < 8; ks++)
            af[mi][ks] = *(const h8*)(h1 + (size_t)(m0 + wr*32 + mi*16 + lr) * 256 + ks*32 + lk);

    f4 acc2[2][8];
    {
        f4 zr = {0.f,0.f,0.f,0.f};
        #pragma unroll
        for (int mi = 0; mi < 2; mi++)
            #pragma unroll
            for (int ni = 0; ni < 8; ni++) acc2[mi][ni] = zr;
    }

    // T14 prefetch registers: one full W1 chunk / W2 chunk per thread (64 elems)
    uint4 pf1[8], pf2[8];
    {
        const _Float16* g = W1p + (size_t)prow * 256 + pcol;   // chunk 0
        #pragma unroll
        for (int q = 0; q < 8; q++) pf1[q] = *(const uint4*)(g + 8*q);
    }

    for (int c = 0; c < 32; c++) {
        __syncthreads();                               // A: WB free
        {   // publish W1 chunk [64][264] from regs (8x b128, 16B-aligned)
            _Float16* d = &WB[prow*264 + pcol];
            #pragma unroll
            for (int q = 0; q < 8; q++) *(uint4*)(d + 8*q) = pf1[q];
        }
        __syncthreads();                               // B: W1 visible
        // T14: issue W2 chunk loads now (hide under GEMM1)
        {
            const _Float16* g = W2p + (size_t)tid * 2048 + c*64;
            #pragma unroll
            for (int q = 0; q < 8; q++) pf2[q] = *(const uint4*)(g + 8*q);
        }
        // ---- GEMM1: z = h1_tile @ W1c^T  (64 x 64), all 8 K-steps ----
        f4 acc1[2][2];
        {
            f4 zr = {0.f,0.f,0.f,0.f};
            acc1[0][0]=zr; acc1[0][1]=zr; acc1[1][0]=zr; acc1[1][1]=zr;
        }
        #pragma unroll
        for (int ks = 0; ks < 8; ks++) {
            const h8 b0 = *(const h8*)&WB[(wc*32 +      lr)*264 + ks*32 + lk];
            const h8 b1f = *(const h8*)&WB[(wc*32 + 16 + lr)*264 + ks*32 + lk];
            acc1[0][0] = __builtin_amdgcn_mfma_f32_16x16x32_f16(af[0][ks], b0,  acc1[0][0], 0, 0, 0);
            acc1[1][0] = __builtin_amdgcn_mfma_f32_16x16x32_f16(af[1][ks], b0,  acc1[1][0], 0, 0, 0);
            acc1[0][1] = __builtin_amdgcn_mfma_f32_16x16x32_f16(af[0][ks], b1f, acc1[0][1], 0, 0, 0);
            acc1[1][1] = __builtin_amdgcn_mfma_f32_16x16x32_f16(af[1][ks], b1f, acc1[1][1], 0, 0, 0);
        }
        // ---- z -> zt with bias+relu (wave's 32x32 quadrant) ----
        #pragma unroll
        for (int ni = 0; ni < 2; ni++) {
            const float bv = b1[c*64 + wc*32 + ni*16 + lr];
            #pragma unroll
            for (int mi = 0; mi < 2; mi++)
                #pragma unroll
                for (int j = 0; j < 4; j++) {
                    float v = acc1[mi][ni][j] + bv;
                    v = fmaxf(v, 0.f);
                    zt[wr*32 + mi*16 + l4 + j][wc*32 + ni*16 + lr] = (_Float16)v;
                }
        }
        __syncthreads();                               // C: zt visible, WB free
        {   // publish W2 chunk [256][68] from regs (16x b64)
            _Float16* d = &WB[tid*68];
            #pragma unroll
            for (int q = 0; q < 8; q++) {
                uint2 ta; ta.x = pf2[q].x; ta.y = pf2[q].y; *(uint2*)(d + 8*q)     = ta;
                uint2 tb; tb.x = pf2[q].z; tb.y = pf2[q].w; *(uint2*)(d + 8*q + 4) = tb;
            }
        }
        __syncthreads();                               // D: W2 visible
        // T14: issue next W1 chunk loads (hide under GEMM2)
        if (c < 31) {
            const _Float16* g = W1p + (size_t)((c+1)*64 + prow) * 256 + pcol;
            #pragma unroll
            for (int q = 0; q < 8; q++) pf1[q] = *(const uint4*)(g + 8*q);
        }
        // ---- GEMM2: acc2 += zt @ W2c^T, K=64 (2 K-steps) ----
        #pragma unroll
        for (int kk = 0; kk < 2; kk++) {
            const h8 a0 = *(const h8*)&zt[wr*32 +      lr][kk*32 + lk];
            const h8 a1 = *(const h8*)&zt[wr*32 + 16 + lr][kk*32 + lk];
            #pragma unroll
            for (int ni = 0; ni < 8; ni++) {
                const _Float16* s = &WB[(wc*128 + ni*16 + lr)*68 + kk*32 + lk];
                uint2 q0 = *(const uint2*)s;
                uint2 q1 = *(const uint2*)(s + 4);
                uint4 u; u.x=q0.x; u.y=q0.y; u.z=q1.x; u.w=q1.y;
                const h8 b = uint4_to_h8(u);
                acc2[0][ni] = __builtin_amdgcn_mfma_f32_16x16x32_f16(a0, b, acc2[0][ni], 0, 0, 0);
                acc2[1][ni] = __builtin_amdgcn_mfma_f32_16x16x32_f16(a1, b, acc2[1][ni], 0, 0, 0);
            }
        }
    }
    // ---- epilogue: res2 = acc2 + b2 + h1 residual ----
    #pragma unroll
    for (int ni = 0; ni < 8; ni++) {
        const int col = wc*128 + ni*16 + lr;
        const float bv = b2[col];
        #pragma unroll
        for (int mi = 0; mi < 2; mi++) {
            const int rl = wr*32 + mi*16 + l4;
            #pragma unroll
            for (int j = 0; j < 4; j++) {
                const size_t idx = (size_t)(m0 + rl + j) * 256 + col;
                res2[idx] = acc2[mi][ni][j] + bv + (float)h1[idx];
            }
        }
    }
}

// ---------- f32 -> fp16 plane convert (strided source) ----------
__global__ void cvt_kernel(const float* __restrict__ src, int ld, int cshift,
                           _Float16* __restrict__ dst, int total)
{
    const int i = blockIdx.x * 256 + threadIdx.x;
    if (i >= total) return;
    const int r = i >> cshift, c = i & ((1 << cshift) - 1);
    dst[i] = (_Float16)src[(size_t)r * ld + c];
}

// ---------------------------------------------------------------------------
// MFMA flash attention per (b, head).  (unchanged from round 9)
// ---------------------------------------------------------------------------
__global__ __launch_bounds__(256) void attn_kernel(const _Float16* __restrict__ qkv,
                                                   _Float16* __restrict__ o)
{
    __shared__ _Float16 Kl[64][68];
    __shared__ _Float16 Vt[64][68];
    __shared__ _Float16 Pl[4][64][68];
    const int b = blockIdx.x, head = blockIdx.y;
    const _Float16* base = qkv + (size_t)b * 768 + head * 64;
    const int tid = threadIdx.x;
    const int lane = tid & 63, wid = tid >> 6;
    const int lr = lane & 15, lg = lane >> 4;
    const int lk = lg << 3;
    const int q0 = wid * 64;

    h8 qf[4][2];
    #pragma unroll
    for (int mi = 0; mi < 4; mi++)
        #pragma unroll
        for (int kk = 0; kk < 2; kk++)
            qf[mi][kk] = *(const h8*)(base + (size_t)(q0 + mi*16 + lr) * 196608 + kk*32 + lk);

    f4 oacc[4][4];
    float m_st[4][4], l_st[4][4];
    {
        f4 zr = {0.f,0.f,0.f,0.f};
        #pragma unroll
        for (int mi = 0; mi < 4; mi++)
            #pragma unroll
            for (int di = 0; di < 4; di++) oacc[mi][di] = zr;
        #pragma unroll
        for (int mi = 0; mi < 4; mi++)
            #pragma unroll
            for (int j = 0; j < 4; j++) { m_st[mi][j] = -1e30f; l_st[mi][j] = 0.f; }
    }

    for (int kt = 0; kt < 4; kt++) {
        __syncthreads();
        {
            const int row = tid >> 2, c0 = (tid & 3) << 4;
            const _Float16* rp = base + (size_t)(kt*64 + row) * 196608;
            *(uint4*)&Kl[row][c0]     = *(const uint4*)(rp + 256 + c0);
            *(uint4*)&Kl[row][c0 + 8] = *(const uint4*)(rp + 256 + c0 + 8);
            const h8 v0 = *(const h8*)(rp + 512 + c0);
            const h8 v1 = *(const h8*)(rp + 512 + c0 + 8);
            #pragma unroll
            for (int j = 0; j < 8; j++) {
                Vt[c0 + j][row]     = v0[j];
                Vt[c0 + 8 + j][row] = v1[j];
            }
        }
        __syncthreads();
        f4 sacc[4][4];
        {
            f4 zr = {0.f,0.f,0.f,0.f};
            #pragma unroll
            for (int mi = 0; mi < 4; mi++)
                #pragma unroll
                for (int ni = 0; ni < 4; ni++) sacc[mi][ni] = zr;
        }
        #pragma unroll
        for (int kk = 0; kk < 2; kk++) {
            h8 kf[4];
            #pragma unroll
            for (int ni = 0; ni < 4; ni++)
                kf[ni] = *(const h8*)&Kl[ni*16 + lr][kk*32 + lk];
            #pragma unroll
            for (int mi = 0; mi < 4; mi++)
                #pragma unroll
                for (int ni = 0; ni < 4; ni++)
                    sacc[mi][ni] = __builtin_amdgcn_mfma_f32_16x16x32_f16(qf[mi][kk], kf[ni], sacc[mi][ni], 0, 0, 0);
        }
        #pragma unroll
        for (int mi = 0; mi < 4; mi++)
            #pragma unroll
            for (int ni = 0; ni < 4; ni++)
                #pragma unroll
                for (int j = 0; j < 4; j++) sacc[mi][ni][j] *= 0.125f;
        #pragma unroll
        for (int mi = 0; mi < 4; mi++) {
            #pragma unroll
            for (int j = 0; j < 4; j++) {
                float tm = fmaxf(fmaxf(sacc[mi][0][j], sacc[mi][1][j]),
                                 fmaxf(sacc[mi][2][j], sacc[mi][3][j]));
                tm = fmaxf(tm, __shfl_xor(tm, 1));
                tm = fmaxf(tm, __shfl_xor(tm, 2));
                tm = fmaxf(tm, __shfl_xor(tm, 4));
                tm = fmaxf(tm, __shfl_xor(tm, 8));
                const float mn = fmaxf(m_st[mi][j], tm);
                const float sc = __expf(m_st[mi][j] - mn);
                m_st[mi][j] = mn;
                float ps = 0.f;
                #pragma unroll
                for (int ni = 0; ni < 4; ni++) {
                    const float p = __expf(sacc[mi][ni][j] - mn);
                    sacc[mi][ni][j] = p;
                    ps += p;
                }
                ps += __shfl_xor(ps, 1);
                ps += __shfl_xor(ps, 2);
                ps += __shfl_xor(ps, 4);
                ps += __shfl_xor(ps, 8);
                l_st[mi][j] = l_st[mi][j] * sc + ps;
                #pragma unroll
                for (int di = 0; di < 4; di++) oacc[mi][di][j] *= sc;
            }
        }
        #pragma unroll
        for (int mi = 0; mi < 4; mi++)
            #pragma unroll
            for (int ni = 0; ni < 4; ni++)
                #pragma unroll
                for (int j = 0; j < 4; j++)
                    Pl[wid][mi*16 + (lg<<2) + j][ni*16 + lr] = (_Float16)sacc[mi][ni][j];
        #pragma unroll
        for (int kk = 0; kk < 2; kk++) {
            h8 pf[4], vf[4];
            #pragma unroll
            for (int mi = 0; mi < 4; mi++)
                pf[mi] = *(const h8*)&Pl[wid][mi*16 + lr][kk*32 + lk];
            #pragma unroll
            for (int di = 0; di < 4; di++)
                vf[di] = *(const h8*)&Vt[di*16 + lr][kk*32 + lk];
            #pragma unroll
            for (int mi = 0; mi < 4; mi++)
                #pragma unroll
                for (int di = 0; di < 4; di++)
                    oacc[mi][di] = __builtin_amdgcn_mfma_f32_16x16x32_f16(pf[mi], vf[di], oacc[mi][di], 0, 0, 0);
        }
    }
    _Float16* obase = o + (size_t)b * 256 + head * 64;
    #pragma unroll
    for (int mi = 0; mi < 4; mi++) {
        #pragma unroll
        for (int j = 0; j < 4; j++) {
            const float inv = 1.f / l_st[mi][j];
            const size_t rowoff = (size_t)(q0 + mi*16 + (lg<<2) + j) * 65536;
            #pragma unroll
            for (int di = 0; di < 4; di++)
                obase[rowoff + di*16 + lr] = (_Float16)(oacc[mi][di][j] * inv);
        }
    }
}

// ---------- LayerNorm; optional fp16-plane addin; f32 or fp16(/plane) out ----------
template<int OPL, typename OT>
__global__ __launch_bounds__(256) void ln_kernel(const float* __restrict__ x,
    const float* __restrict__ g, const float* __restrict__ bt,
    const _Float16* __restrict__ addin, const _Float16* __restrict__ addinLo,
    OT* __restrict__ out, long oplane, int nrows)
{
    const int gid = blockIdx.x * 256 + threadIdx.x;
    const int row = gid >> 6;
    const int lane = threadIdx.x & 63;
    if (row >= nrows) return;
    const float* xr = x + (size_t)row * 256;
    float4 v = *(const float4*)(xr + (lane<<2));
    float s = v.x + v.y + v.z + v.w;
    #pragma unroll
    for (int off = 32; off > 0; off >>= 1) s += __shfl_xor(s, off, 64);
    const float mean = s * (1.0f/256.0f);
    const float dx = v.x-mean, dy = v.y-mean, dz = v.z-mean, dw = v.w-mean;
    float ss = dx*dx + dy*dy + dz*dz + dw*dw;
    #pragma unroll
    for (int off = 32; off > 0; off >>= 1) ss += __shfl_xor(ss, off, 64);
    const float inv = rsqrtf(ss * (1.0f/256.0f) + 1e-5f);
    const float4 gv = *(const float4*)(g + (lane<<2));
    const float4 bv = *(const float4*)(bt + (lane<<2));
    float ov[4];
    ov[0] = dx*inv*gv.x + bv.x;
    ov[1] = dy*inv*gv.y + bv.y;
    ov[2] = dz*inv*gv.z + bv.z;
    ov[3] = dw*inv*gv.w + bv.w;
    const size_t base = (size_t)row*256 + (lane<<2);
    if (addin) {
        #pragma unroll
        for (int j = 0; j < 4; j++) {
            ov[j] += (float)addin[base+j];
            if (addinLo) ov[j] += (float)addinLo[base+j];
        }
    }
    #pragma unroll
    for (int j = 0; j < 4; j++) {
        if (OPL) {
            _Float16 hh = (_Float16)ov[j];
            ((_Float16*)out)[base+j] = hh;
            ((_Float16*)out)[base+j+oplane] = (_Float16)(ov[j] - (float)hh);
        } else if (sizeof(OT) == 2) {
            ((_Float16*)out)[base+j] = (_Float16)ov[j];
        } else {
            ((float*)out)[base+j] = ov[j];
        }
    }
}

// ---------- masked softmax over i for e[b][t][i], in place, fp32 ----------
__global__ __launch_bounds__(256) void smax_kernel(float* __restrict__ e,
                                                   const int* __restrict__ seqlen)
{
    const int gid = blockIdx.x * 256 + threadIdx.x;
    const int row = gid >> 6;               // row = b*256 + t
    const int lane = threadIdx.x & 63;
    const int L = seqlen[row >> 8];
    float* er = e + (size_t)row * 256;
    float4 v = *(const float4*)(er + (lane<<2));
    const int i0 = lane << 2;
    const float x0 = (i0+0 < L) ? v.x : -1e30f;
    const float x1 = (i0+1 < L) ? v.y : -1e30f;
    const float x2 = (i0+2 < L) ? v.z : -1e30f;
    const float x3 = (i0+3 < L) ? v.w : -1e30f;
    float mx = fmaxf(fmaxf(x0,x1), fmaxf(x2,x3));
    #pragma unroll
    for (int off = 32; off > 0; off >>= 1) mx = fmaxf(mx, __shfl_xor(mx, off, 64));
    const float p0 = (i0+0 < L) ? __expf(x0-mx) : 0.f;
    const float p1 = (i0+1 < L) ? __expf(x1-mx) : 0.f;
    const float p2 = (i0+2 < L) ? __expf(x2-mx) : 0.f;
    const float p3 = (i0+3 < L) ? __expf(x3-mx) : 0.f;
    float s = p0+p1+p2+p3;
    #pragma unroll
    for (int off = 32; off > 0; off >>= 1) s += __shfl_xor(s, off, 64);
    const float inv = 1.f / s;
    v.x = p0*inv; v.y = p1*inv; v.z = p2*inv; v.w = p3*inv;
    *(float4*)(er + (lane<<2)) = v;
}

// ---------- head: logits (512->7) + log_softmax + ragged scatter; hid fp16 ----------
__global__ __launch_bounds__(256) void head_kernel(const _Float16* __restrict__ hidden,
    const float* __restrict__ Wsm, const float* __restrict__ bsm,
    const int* __restrict__ seqlen, const int* __restrict__ offs,
    float* __restrict__ out)
{
    const int gid = blockIdx.x * 256 + threadIdx.x;
    const int row = gid >> 6;
    const int lane = threadIdx.x & 63;
    if (row >= MTB) return;
    const int t = row >> 8, b = row & 255;
    if (t >= seqlen[b]) return;
    const _Float16* hr = hidden + (size_t)row * 512;
    const h8 hu = *(const h8*)(hr + lane*8);
    float hv[8];
    #pragma unroll
    for (int j = 0; j < 8; j++) hv[j] = (float)hu[j];
    float lg[7];
    #pragma unroll
    for (int c = 0; c < 7; c++) {
        const float* wr = Wsm + c*512 + lane*8;
        const float4 w0 = *(const float4*)wr;
        const float4 w1 = *(const float4*)(wr + 4);
        float acc = hv[0]*w0.x + hv[1]*w0.y + hv[2]*w0.z + hv[3]*w0.w
                  + hv[4]*w1.x + hv[5]*w1.y + hv[6]*w1.z + hv[7]*w1.w;
        #pragma unroll
        for (int off = 32; off > 0; off >>= 1) acc += __shfl_xor(acc, off, 64);
        lg[c] = acc + bsm[c];
    }
    float mx = lg[0];
    #pragma unroll
    for (int c = 1; c < 7; c++) mx = fmaxf(mx, lg[c]);
    float s = 0.f;
    #pragma unroll
    for (int c = 0; c < 7; c++) s += __expf(lg[c] - mx);
    const float lse = mx + logf(s);
    if (lane == 0) {
        float* orow = out + (size_t)(offs[b] + t) * 7;
        #pragma unroll
        for (int c = 0; c < 7; c++) orow[c] = lg[c] - lse;
    }
}

// ---------- positional encoding over the BATCH dim (faithful quirk) ----------
__global__ void pe_kernel(float* __restrict__ pe)
{
    const int idx = blockIdx.x * 256 + threadIdx.x;   // 65536 = 256x256
    const int b = idx >> 8, f = idx & 255;
    const int j = f >> 1;
    const float div = expf(-9.210340371976184f * (2.0f * j) * (1.0f/256.0f));
    const float arg = (float)b * div;
    pe[idx] = (f & 1) ? cosf(arg) : sinf(arg);
}

// ---------- exclusive prefix sum of seq lengths ----------
__global__ void prefix_kernel(const int* __restrict__ L, int* __restrict__ offs)
{
    if (threadIdx.x == 0) {
        int acc = 0;
        for (int i = 0; i < 256; i++) { offs[i] = acc; acc += L[i]; }
        offs[256] = acc;
    }
}

// ---------- diagnostic: report ws_size via absmax if insufficient ----------
__global__ void sentinel_kernel(float* __restrict__ out, float v)
{
    if (threadIdx.x == 0) out[0] = v;
}

// ---------------------------------------------------------------------------
extern "C" void kernel_launch(void* const* d_in, const int* in_sizes, int n_in,
                              void* d_out, int out_size, void* d_ws, size_t ws_size,
                              hipStream_t stream)
{
    const float* U_s   = (const float*)d_in[0];
    const float* U_p   = (const float*)d_in[1];
    const float* W_emb = (const float*)d_in[2];
    const float* b_emb = (const float*)d_in[3];
    const float* Wqkv  = (const float*)d_in[4];
    const float* bqkv  = (const float*)d_in[5];
    const float* Wo    = (const float*)d_in[6];
    const float* bo    = (const float*)d_in[7];
    const float* ln1_g = (const float*)d_in[8];
    const float* ln1_b = (const float*)d_in[9];
    const float* W1    = (const float*)d_in[10];
    const float* b1    = (const float*)d_in[11];
    const float* W2    = (const float*)d_in[12];
    const float* b2    = (const float*)d_in[13];
    const float* ln2_g = (const float*)d_in[14];
    const float* ln2_b = (const float*)d_in[15];
    const float* W_fc  = (const float*)d_in[16];
    const float* b_fc  = (const float*)d_in[17];
    const float* W_sm  = (const float*)d_in[18];
    const float* b_sm  = (const float*)d_in[19];
    const int*   seqlen= (const int*)d_in[20];
    float* out = (float*)d_out;

    // ---- aliased workspace arena, peak 193 MiB ----
    const size_t MiB = 1024*1024;
    const size_t KiB = 1024;
    char* ws = (char*)d_ws;
    if (ws_size < 193*MiB) {
        sentinel_kernel<<<dim3(1), dim3(64), 0, stream>>>(out, -(float)(ws_size / MiB));
        return;
    }
    const long PL = 16*1024*1024;                        // plane stride (elems)
    _Float16* h_hi = (_Float16*)(ws);                    // [0,32M)
    _Float16* h_lo = (_Float16*)(ws + 32*MiB);           // [32,64M)
    int*      offs = (int*)(ws + 64*MiB);                // 4 KiB
    char*     slot = ws + 64*MiB + 8*KiB;                // <1 MiB weight slot
    _Float16* qkv  = (_Float16*)(ws + 65*MiB);           // [65,161M), dead after attn
    _Float16* o    = (_Float16*)(ws + 161*MiB);          // [161,193M), dead after proj
    float*    res1 = (float*)(ws + 65*MiB);              // [65,129M) f32 (over dead qkv)
    float*    res2 = res1;
    _Float16* h1   = (_Float16*)(ws + 161*MiB);          // [161,193M) (over dead o)
    _Float16* w1p  = (_Float16*)(ws + 129*MiB);          // [129,130M) FF weights (fp16)
    _Float16* w2p  = (_Float16*)(ws + 130*MiB);          // [130,131M)
    _Float16* q_hi = (_Float16*)(ws + 129*MiB);          // [129,161M) (over dead w1p/w2p)
    _Float16* q_lo = (_Float16*)(ws + 161*MiB);          // [161,193M) (over dead h1)
    float*    e    = (float*)(ws + 65*MiB);              // [65,129M)  (over dead res2)
    _Float16* r    = (_Float16*)(ws);                    // [0,32M)    (over dead h planes)
    _Float16* hid  = (_Float16*)(ws + 129*MiB);          // [129,193M) (over dead q planes)

    prefix_kernel<<<dim3(1), dim3(64), 0, stream>>>(seqlen, offs);

    _Float16* wp  = (_Float16*)slot;                     // rotating weight plane
    float*    pe  = (float*)(slot + 512*KiB);            // 256 KiB, embed only

    // --- embed: h(planes) = mask(U_s) @ W_emb^T + b_emb + pe[b,:] ---
    cvt_kernel<<<dim3(256), 256, 0, stream>>>(W_emb, 256, 8, wp, 65536);
    pe_kernel<<<dim3(256), dim3(256), 0, stream>>>(pe);
    gemm_h<E_BIAS|E_PE|E_MASKA, 0, 2, _Float16, 1, float, 0>
        <<<dim3(2,512,1), 256, 0, stream>>>(
        MTB,256,256, U_s,nullptr,256,0, wp,256,0, h_hi,PL,256,0,
        b_emb, (const float*)nullptr, nullptr, pe, seqlen);

    // --- qkv = h @ Wqkv^T + bqkv (fp16) ---
    cvt_kernel<<<dim3(768), 256, 0, stream>>>(Wqkv, 256, 8, wp, 196608);
    gemm_h<E_BIAS, 2, 2, _Float16, 0, float, 0>
        <<<dim3(6,512,1), 256, 0, stream>>>(
        MTB,768,256, h_hi,nullptr,256,0, wp,256,0, qkv,0,768,0,
        bqkv, (const float*)nullptr, nullptr, nullptr, nullptr);

    // --- MFMA flash attention -> o [T,B,256] fp16 ---
    attn_kernel<<<dim3(256,4), 256, 0, stream>>>(qkv, o);

    // --- res1 = o @ Wo^T + bo + h(planes) ---
    cvt_kernel<<<dim3(256), 256, 0, stream>>>(Wo, 256, 8, wp, 65536);
    gemm_h<E_BIAS|E_RES, 2, 2, float, 0, _Float16, 1>
        <<<dim3(2,512,1), 256, 0, stream>>>(
        MTB,256,256, o,nullptr,256,0, wp,256,0, res1,0,256,0,
        bo, h_hi, h_lo, nullptr, nullptr);

    // --- h1 = LN1(res1) (fp16) ---
    ln_kernel<0, _Float16><<<dim3(MTB/4), 256, 0, stream>>>(
        res1, ln1_g, ln1_b, nullptr, nullptr, h1, 0, MTB);

    // --- fused FF v6: res2 = h1 + relu(h1@W1^T+b1)@W2^T + b2 ---
    cvt_kernel<<<dim3(2048), 256, 0, stream>>>(W1, 256, 8, w1p, 524288);
    cvt_kernel<<<dim3(2048), 256, 0, stream>>>(W2, 2048, 11, w2p, 524288);
    ff_kernel<<<dim3(1024), 256, 0, stream>>>(h1, w1p, w2p, b1, b2, res2);

    // --- q(planes) = h(planes) + LN2(res2) ---
    ln_kernel<1, _Float16><<<dim3(MTB/4), 256, 0, stream>>>(
        res2, ln2_g, ln2_b, h_hi, h_lo, q_hi, PL, MTB);

    // --- e[b][t][i] = q . U_p  (3-pass split-fp16, fp32-class) ---
    gemm_h<0, 3, 0, float, 0, float, 0>
        <<<dim3(2,2,256), 256, 0, stream>>>(
        256,256,256, q_hi,q_lo,65536,256, U_p,65536,256, e,0,256,65536,
        nullptr, (const float*)nullptr, nullptr, nullptr, nullptr);

    // --- masked softmax over i ---
    smax_kernel<<<dim3(MTB/4), 256, 0, stream>>>(e, seqlen);

    // --- r = a @ U_p (fp16 out) ---
    gemm_h<0, 0, 1, _Float16, 0, float, 0>
        <<<dim3(2,2,256), 256, 0, stream>>>(
        256,256,256, e,nullptr,256,65536, U_p,65536,256, r,0,65536,256,
        nullptr, (const float*)nullptr, nullptr, nullptr, nullptr);

    // --- hidden = relu([mask(U_s), r] @ W_fc^T + b_fc) fp16, fused K=512 ---
    cvt_kernel<<<dim3(1024), 256, 0, stream>>>(W_fc, 512, 9, wp, 262144);
    gemm_h<E_BIAS|E_RELU|E_MASKA, 4, 2, _Float16, 0, float, 0>
        <<<dim3(4,512,1), 256, 0, stream>>>(
        MTB,512,512, U_s,r,256,0, wp,512,0, hid,0,512,0,
        b_fc, (const float*)nullptr, nullptr, nullptr, seqlen);

    // --- logits + log_softmax + ragged gather ---
    head_kernel<<<dim3(MTB/4), 256, 0, stream>>>(hid, W_sm, b_sm, seqlen, offs, out);
}

// Round 14
// 923.932 us; speedup vs baseline: 1.3502x; 1.3502x over previous
//
#include <hip/hip_runtime.h>

#define MTB 65536   // T*B rows

typedef unsigned int uint;
typedef unsigned short ushort;

typedef _Float16 h8 __attribute__((ext_vector_type(8)));   // 8 fp16 (4 VGPR)
typedef __attribute__((ext_vector_type(4))) float f4;      // mfma accumulator

enum { E_BIAS=1, E_RELU=2, E_ACC=4, E_RES=8, E_PE=16, E_MASKA=32 };

__device__ __forceinline__ float ldsc(const float* p) { return *p; }
__device__ __forceinline__ float ldsc(const _Float16* p) { return (float)*p; }

__device__ __forceinline__ h8 uint4_to_h8(uint4 u) { return __builtin_bit_cast(h8, u); }

// ---------------------------------------------------------------------------
// fp16 MFMA GEMM: C = A @ W^T (+epilogue), 128x128 tile, BK=32.
// SWZ=1: XCD-aware bijective block remap (requires gridDim.x*gridDim.y % 8 == 0,
// gridDim.z == 1) so each XCD L2 gets a contiguous M-range (A-panel locality).
// ---------------------------------------------------------------------------
template<int EPI, int AMODE, int BMODE, typename CT, int CPL, typename RT, int RPL, int SWZ>
__global__ __launch_bounds__(256) void gemm_h(
    int M, int N, int K,
    const void* __restrict__ Ap, const void* __restrict__ Ap2, int lda, long batchA,
    const void* __restrict__ Bp, int ldw, long batchW,
    CT* __restrict__ C, long cplane, int ldc, long batchC,
    const float* __restrict__ bias,
    const RT* __restrict__ res, const RT* __restrict__ resLo,
    const float* __restrict__ pe,
    const int* __restrict__ seqlen)
{
    __shared__ _Float16 Ah[128][40];
    __shared__ _Float16 Al[(AMODE==3)?128:1][40];
    __shared__ _Float16 Bh[128][40];
    __shared__ _Float16 Bl[(BMODE==0)?128:1][40];

    const int z = blockIdx.z;
    C += (size_t)z * batchC;
    const float*    Af  = (const float*)Ap + (AMODE==0 ? (size_t)z*batchA : 0);
    const _Float16* Ahp = (const _Float16*)Ap + ((AMODE==2||AMODE==3) ? (size_t)z*batchA : 0);
    const _Float16* Alp = (const _Float16*)Ap2 + (AMODE==3 ? (size_t)z*batchA : 0);
    const float*    Bf  = (const float*)Bp + (BMODE!=2 ? (size_t)z*batchW : 0);
    const _Float16* Bhp = (const _Float16*)Bp;

    int bx = blockIdx.x, by = blockIdx.y;
    if (SWZ) {
        const int gx = gridDim.x;
        const int nwg = gx * gridDim.y;
        const int per = nwg >> 3;
        const int id = by * gx + bx;
        const int nid = (id & 7) * per + (id >> 3);
        bx = nid % gx; by = nid / gx;
    }
    const int m0 = by * 128, n0 = bx * 128;
    const int tid = threadIdx.x;
    const int lane = tid & 63, wid = tid >> 6;
    const int wr = wid >> 1, wc = wid & 1;

    f4 acc[4][4];
    {
        f4 zr = {0.f, 0.f, 0.f, 0.f};
        #pragma unroll
        for (int i = 0; i < 4; i++)
            #pragma unroll
            for (int j = 0; j < 4; j++) acc[i][j] = zr;
    }

    for (int k0 = 0; k0 < K; k0 += 32) {
        __syncthreads();
        // ---- stage A ----
        if (AMODE == 0 || (AMODE == 4 && k0 < 256)) {
            #pragma unroll
            for (int i = 0; i < 4; i++) {
                const int row = i*32 + (tid>>3);
                const int cg  = (tid&7)<<2;
                const int m = m0 + row;
                float4 v; v.x=0.f; v.y=0.f; v.z=0.f; v.w=0.f;
                bool ok = true;
                if (EPI & E_MASKA) ok = ((m>>8) < seqlen[m&255]);
                if (ok) v = *(const float4*)(Af + (size_t)m*lda + k0 + cg);
                Ah[row][cg+0] = (_Float16)v.x;
                Ah[row][cg+1] = (_Float16)v.y;
                Ah[row][cg+2] = (_Float16)v.z;
                Ah[row][cg+3] = (_Float16)v.w;
            }
        } else if (AMODE == 4) {
            const _Float16* Ar = (const _Float16*)Ap2;
            const int row = tid >> 1;
            const int cg  = (tid & 1) << 4;
            const size_t off = (size_t)(m0 + row) * 256 + (k0 - 256) + cg;
            *(uint4*)&Ah[row][cg]     = *(const uint4*)(Ar + off);
            *(uint4*)&Ah[row][cg + 8] = *(const uint4*)(Ar + off + 8);
        } else {
            const int row = tid >> 1;
            const int cg  = (tid & 1) << 4;
            const size_t off = (size_t)(m0 + row) * lda + k0 + cg;
            *(uint4*)&Ah[row][cg]     = *(const uint4*)(Ahp + off);
            *(uint4*)&Ah[row][cg + 8] = *(const uint4*)(Ahp + off + 8);
            if (AMODE == 3) {
                *(uint4*)&Al[row][cg]     = *(const uint4*)(Alp + off);
                *(uint4*)&Al[row][cg + 8] = *(const uint4*)(Alp + off + 8);
            }
        }
        // ---- stage B ----
        if (BMODE == 2) {
            const int row = tid >> 1;
            const int cg  = (tid & 1) << 4;
            const size_t off = (size_t)(n0 + row) * ldw + k0 + cg;
            *(uint4*)&Bh[row][cg]     = *(const uint4*)(Bhp + off);
            *(uint4*)&Bh[row][cg + 8] = *(const uint4*)(Bhp + off + 8);
        } else if (BMODE == 0) {
            #pragma unroll
            for (int i = 0; i < 4; i++) {
                const int row = i*32 + (tid>>3);
                const int cg  = (tid&7)<<2;
                float4 v = *(const float4*)(Bf + (size_t)(n0+row)*ldw + k0 + cg);
                _Float16 h0 = (_Float16)v.x, h1 = (_Float16)v.y,
                         h2 = (_Float16)v.z, h3 = (_Float16)v.w;
                Bh[row][cg+0]=h0; Bl[row][cg+0]=(_Float16)(v.x-(float)h0);
                Bh[row][cg+1]=h1; Bl[row][cg+1]=(_Float16)(v.y-(float)h1);
                Bh[row][cg+2]=h2; Bl[row][cg+2]=(_Float16)(v.z-(float)h2);
                Bh[row][cg+3]=h3; Bl[row][cg+3]=(_Float16)(v.w-(float)h3);
            }
        } else {  // BMODE == 1 : W f32 [K,N], transpose + cvt
            #pragma unroll
            for (int i = 0; i < 4; i++) {
                const int kr = i*8 + (tid>>5);
                const int ng = (tid&31)<<2;
                float4 v = *(const float4*)(Bf + (size_t)(k0+kr)*ldw + n0 + ng);
                Bh[ng+0][kr] = (_Float16)v.x;
                Bh[ng+1][kr] = (_Float16)v.y;
                Bh[ng+2][kr] = (_Float16)v.z;
                Bh[ng+3][kr] = (_Float16)v.w;
            }
        }
        __syncthreads();
        // ---- fragments + MFMA ----
        const int lr = lane & 15, lk = (lane>>4)<<3;
        h8 ah[4], bh[4];
        #pragma unroll
        for (int i = 0; i < 4; i++) {
            ah[i] = *(const h8*)&Ah[wr*64 + i*16 + lr][lk];
            bh[i] = *(const h8*)&Bh[wc*64 + i*16 + lr][lk];
        }
        #pragma unroll
        for (int mi = 0; mi < 4; mi++)
            #pragma unroll
            for (int ni = 0; ni < 4; ni++)
                acc[mi][ni] = __builtin_amdgcn_mfma_f32_16x16x32_f16(ah[mi], bh[ni], acc[mi][ni], 0, 0, 0);
        if (AMODE == 3) {
            h8 al[4], bl[4];
            #pragma unroll
            for (int i = 0; i < 4; i++) {
                al[i] = *(const h8*)&Al[wr*64 + i*16 + lr][lk];
                bl[i] = *(const h8*)&Bl[wc*64 + i*16 + lr][lk];
            }
            #pragma unroll
            for (int mi = 0; mi < 4; mi++)
                #pragma unroll
                for (int ni = 0; ni < 4; ni++) {
                    acc[mi][ni] = __builtin_amdgcn_mfma_f32_16x16x32_f16(ah[mi], bl[ni], acc[mi][ni], 0, 0, 0);
                    acc[mi][ni] = __builtin_amdgcn_mfma_f32_16x16x32_f16(al[mi], bh[ni], acc[mi][ni], 0, 0, 0);
                }
        }
    }
    // ---- epilogue: C row = 4*(lane>>4)+reg, col = lane&15 ----
    const int colb = n0 + wc*64;
    const int rowb = m0 + wr*64;
    #pragma unroll
    for (int ni = 0; ni < 4; ni++) {
        const int col = colb + ni*16 + (lane & 15);
        float bv = (EPI & E_BIAS) ? bias[col] : 0.f;
        #pragma unroll
        for (int mi = 0; mi < 4; mi++) {
            const int r0 = rowb + mi*16 + ((lane>>4)<<2);
            #pragma unroll
            for (int j = 0; j < 4; j++) {
                const int row = r0 + j;
                const size_t idx = (size_t)row*ldc + col;
                float v = acc[mi][ni][j] + bv;
                if (EPI & E_PE)  v += pe[((row & 255) << 8) + col];
                if (EPI & E_RES) {
                    v += ldsc(res + idx);
                    if (RPL) v += ldsc(resLo + idx);
                }
                CT* cp = C + idx;
                if (EPI & E_ACC) v += ldsc((const CT*)cp);
                if (EPI & E_RELU) v = fmaxf(v, 0.f);
                if (CPL) {
                    _Float16 hh = (_Float16)v;
                    *(_Float16*)cp = hh;
                    *((_Float16*)cp + cplane) = (_Float16)(v - (float)hh);
                } else if (sizeof(CT) == 2) {
                    *(_Float16*)cp = (_Float16)v;
                } else {
                    *(float*)cp = v;
                }
            }
        }
    }
}

// ---------------------------------------------------------------------------
// Fused FF v5 (round-12 proven): zt LDS, all-16x16x32, T14 rolling prefetch,
// 36-stride Bs, register A-fragments. 64 h-rows per block.
// ---------------------------------------------------------------------------
__global__ __launch_bounds__(256) void ff_kernel(
    const _Float16* __restrict__ h1,    // [65536][256] fp16
    const _Float16* __restrict__ W1p,   // [2048][256] fp16
    const _Float16* __restrict__ W2p,   // [256][2048] fp16
    const float* __restrict__ b1,
    const float* __restrict__ b2,
    float* __restrict__ res2)           // [65536][256] f32
{
    __shared__ _Float16 Bs[256][36];    // 18.4 KB
    __shared__ _Float16 zt[64][136];    // 17.4 KB
    const int m0 = blockIdx.x * 64;
    const int tid = threadIdx.x;
    const int lane = tid & 63, wid = tid >> 6;
    const int wr = wid >> 1, wc = wid & 1;
    const int lr = lane & 15, lg = lane >> 4;
    const int lk = lg << 3;
    const int l4 = lg << 2;
    const int srow = tid >> 1, sh = tid & 1;   // W1 staging mapping

    h8 af[2][8];
    #pragma unroll
    for (int mi = 0; mi < 2; mi++)
        #pragma unroll
        for (int ks = 0; ks < 8; ks++)
            af[mi][ks] = *(const h8*)(h1 + (size_t)(m0 + wr*32 + mi*16 + lr) * 256 + ks*32 + lk);

    f4 acc2[2][8];
    {
        f4 zr = {0.f,0.f,0.f,0.f};
        #pragma unroll
        for (int mi = 0; mi < 2; mi++)
            #pragma unroll
            for (int ni = 0; ni < 8; ni++) acc2[mi][ni] = zr;
    }

    uint4 p1a, p1b;      // W1 piece: 16 fp16/thread
    uint4 p2[4];         // W2 piece: 32 fp16/thread
    {
        const _Float16* g = W1p + (size_t)srow * 256 + sh*16;   // c=0, ks=0
        p1a = *(const uint4*)g; p1b = *(const uint4*)(g + 8);
    }

    for (int c = 0; c < 16; c++) {
        f4 acc1[2][4];
        {
            f4 zr = {0.f,0.f,0.f,0.f};
            #pragma unroll
            for (int mi = 0; mi < 2; mi++)
                #pragma unroll
                for (int ni = 0; ni < 4; ni++) acc1[mi][ni] = zr;
        }
        for (int ks = 0; ks < 8; ks++) {
            __syncthreads();
            {
                _Float16* d = &Bs[srow][sh*16];
                uint2 t0; t0.x=p1a.x; t0.y=p1a.y; *(uint2*)(d+0)  = t0;
                uint2 t1; t1.x=p1a.z; t1.y=p1a.w; *(uint2*)(d+4)  = t1;
                uint2 t2; t2.x=p1b.x; t2.y=p1b.y; *(uint2*)(d+8)  = t2;
                uint2 t3; t3.x=p1b.z; t3.y=p1b.w; *(uint2*)(d+12) = t3;
            }
            __syncthreads();
            if (ks < 7) {
                const _Float16* g = W1p + (size_t)(c*128 + srow) * 256 + (ks+1)*32 + sh*16;
                p1a = *(const uint4*)g; p1b = *(const uint4*)(g + 8);
            } else {
                const _Float16* g = W2p + (size_t)tid * 2048 + c*128;
                #pragma unroll
                for (int q = 0; q < 4; q++) p2[q] = *(const uint4*)(g + 8*q);
            }
            #pragma unroll
            for (int ni = 0; ni < 4; ni++) {
                const _Float16* s = &Bs[wc*64 + ni*16 + lr][lk];
                uint2 q0 = *(const uint2*)s;
                uint2 q1 = *(const uint2*)(s + 4);
                uint4 u; u.x=q0.x; u.y=q0.y; u.z=q1.x; u.w=q1.y;
                const h8 b = uint4_to_h8(u);
                acc1[0][ni] = __builtin_amdgcn_mfma_f32_16x16x32_f16(af[0][ks], b, acc1[0][ni], 0, 0, 0);
                acc1[1][ni] = __builtin_amdgcn_mfma_f32_16x16x32_f16(af[1][ks], b, acc1[1][ni], 0, 0, 0);
            }
        }
        #pragma unroll
        for (int ni = 0; ni < 4; ni++) {
            const float bv = b1[c*128 + wc*64 + ni*16 + lr];
            #pragma unroll
            for (int mi = 0; mi < 2; mi++)
                #pragma unroll
                for (int j = 0; j < 4; j++) {
                    float v = acc1[mi][ni][j] + bv;
                    v = fmaxf(v, 0.f);
                    zt[wr*32 + mi*16 + l4 + j][wc*64 + ni*16 + lr] = (_Float16)v;
                }
        }
        __syncthreads();
        for (int kk = 0; kk < 4; kk++) {
            if (kk) __syncthreads();
            {
                _Float16* d = &Bs[tid][0];
                #pragma unroll
                for (int q = 0; q < 4; q++) {
                    uint2 ta; ta.x=p2[q].x; ta.y=p2[q].y; *(uint2*)(d + 8*q)     = ta;
                    uint2 tb; tb.x=p2[q].z; tb.y=p2[q].w; *(uint2*)(d + 8*q + 4) = tb;
                }
            }
            __syncthreads();
            if (kk < 3) {
                const _Float16* g = W2p + (size_t)tid * 2048 + c*128 + (kk+1)*32;
                #pragma unroll
                for (int q = 0; q < 4; q++) p2[q] = *(const uint4*)(g + 8*q);
            } else if (c < 15) {
                const _Float16* g = W1p + (size_t)((c+1)*128 + srow) * 256 + sh*16;
                p1a = *(const uint4*)g; p1b = *(const uint4*)(g + 8);
            }
            const h8 a0 = *(const h8*)&zt[wr*32 +      lr][kk*32 + lk];
            const h8 a1 = *(const h8*)&zt[wr*32 + 16 + lr][kk*32 + lk];
            #pragma unroll
            for (int ni = 0; ni < 8; ni++) {
                const _Float16* s = &Bs[wc*128 + ni*16 + lr][lk];
                uint2 q0 = *(const uint2*)s;
                uint2 q1 = *(const uint2*)(s + 4);
                uint4 u; u.x=q0.x; u.y=q0.y; u.z=q1.x; u.w=q1.y;
                const h8 b = uint4_to_h8(u);
                acc2[0][ni] = __builtin_amdgcn_mfma_f32_16x16x32_f16(a0, b, acc2[0][ni], 0, 0, 0);
                acc2[1][ni] = __builtin_amdgcn_mfma_f32_16x16x32_f16(a1, b, acc2[1][ni], 0, 0, 0);
            }
        }
    }
    #pragma unroll
    for (int ni = 0; ni < 8; ni++) {
        const int col = wc*128 + ni*16 + lr;
        const float bv = b2[col];
        #pragma unroll
        for (int mi = 0; mi < 2; mi++) {
            const int rl = wr*32 + mi*16 + l4;
            #pragma unroll
            for (int j = 0; j < 4; j++) {
                const size_t idx = (size_t)(m0 + rl + j) * 256 + col;
                res2[idx] = acc2[mi][ni][j] + bv + (float)h1[idx];
            }
        }
    }
}

// ---------- f32 -> fp16 plane convert (strided source) ----------
__global__ void cvt_kernel(const float* __restrict__ src, int ld, int cshift,
                           _Float16* __restrict__ dst, int total)
{
    const int i = blockIdx.x * 256 + threadIdx.x;
    if (i >= total) return;
    const int r = i >> cshift, c = i & ((1 << cshift) - 1);
    dst[i] = (_Float16)src[(size_t)r * ld + c];
}

// ---------------------------------------------------------------------------
// MFMA flash attention per (b, head).  (unchanged from round 9)
// ---------------------------------------------------------------------------
__global__ __launch_bounds__(256) void attn_kernel(const _Float16* __restrict__ qkv,
                                                   _Float16* __restrict__ o)
{
    __shared__ _Float16 Kl[64][68];
    __shared__ _Float16 Vt[64][68];
    __shared__ _Float16 Pl[4][64][68];
    const int b = blockIdx.x, head = blockIdx.y;
    const _Float16* base = qkv + (size_t)b * 768 + head * 64;
    const int tid = threadIdx.x;
    const int lane = tid & 63, wid = tid >> 6;
    const int lr = lane & 15, lg = lane >> 4;
    const int lk = lg << 3;
    const int q0 = wid * 64;

    h8 qf[4][2];
    #pragma unroll
    for (int mi = 0; mi < 4; mi++)
        #pragma unroll
        for (int kk = 0; kk < 2; kk++)
            qf[mi][kk] = *(const h8*)(base + (size_t)(q0 + mi*16 + lr) * 196608 + kk*32 + lk);

    f4 oacc[4][4];
    float m_st[4][4], l_st[4][4];
    {
        f4 zr = {0.f,0.f,0.f,0.f};
        #pragma unroll
        for (int mi = 0; mi < 4; mi++)
            #pragma unroll
            for (int di = 0; di < 4; di++) oacc[mi][di] = zr;
        #pragma unroll
        for (int mi = 0; mi < 4; mi++)
            #pragma unroll
            for (int j = 0; j < 4; j++) { m_st[mi][j] = -1e30f; l_st[mi][j] = 0.f; }
    }

    for (int kt = 0; kt < 4; kt++) {
        __syncthreads();
        {
            const int row = tid >> 2, c0 = (tid & 3) << 4;
            const _Float16* rp = base + (size_t)(kt*64 + row) * 196608;
            *(uint4*)&Kl[row][c0]     = *(const uint4*)(rp + 256 + c0);
            *(uint4*)&Kl[row][c0 + 8] = *(const uint4*)(rp + 256 + c0 + 8);
            const h8 v0 = *(const h8*)(rp + 512 + c0);
            const h8 v1 = *(const h8*)(rp + 512 + c0 + 8);
            #pragma unroll
            for (int j = 0; j < 8; j++) {
                Vt[c0 + j][row]     = v0[j];
                Vt[c0 + 8 + j][row] = v1[j];
            }
        }
        __syncthreads();
        f4 sacc[4][4];
        {
            f4 zr = {0.f,0.f,0.f,0.f};
            #pragma unroll
            for (int mi = 0; mi < 4; mi++)
                #pragma unroll
                for (int ni = 0; ni < 4; ni++) sacc[mi][ni] = zr;
        }
        #pragma unroll
        for (int kk = 0; kk < 2; kk++) {
            h8 kf[4];
            #pragma unroll
            for (int ni = 0; ni < 4; ni++)
                kf[ni] = *(const h8*)&Kl[ni*16 + lr][kk*32 + lk];
            #pragma unroll
            for (int mi = 0; mi < 4; mi++)
                #pragma unroll
                for (int ni = 0; ni < 4; ni++)
                    sacc[mi][ni] = __builtin_amdgcn_mfma_f32_16x16x32_f16(qf[mi][kk], kf[ni], sacc[mi][ni], 0, 0, 0);
        }
        #pragma unroll
        for (int mi = 0; mi < 4; mi++)
            #pragma unroll
            for (int ni = 0; ni < 4; ni++)
                #pragma unroll
                for (int j = 0; j < 4; j++) sacc[mi][ni][j] *= 0.125f;
        #pragma unroll
        for (int mi = 0; mi < 4; mi++) {
            #pragma unroll
            for (int j = 0; j < 4; j++) {
                float tm = fmaxf(fmaxf(sacc[mi][0][j], sacc[mi][1][j]),
                                 fmaxf(sacc[mi][2][j], sacc[mi][3][j]));
                tm = fmaxf(tm, __shfl_xor(tm, 1));
                tm = fmaxf(tm, __shfl_xor(tm, 2));
                tm = fmaxf(tm, __shfl_xor(tm, 4));
                tm = fmaxf(tm, __shfl_xor(tm, 8));
                const float mn = fmaxf(m_st[mi][j], tm);
                const float sc = __expf(m_st[mi][j] - mn);
                m_st[mi][j] = mn;
                float ps = 0.f;
                #pragma unroll
                for (int ni = 0; ni < 4; ni++) {
                    const float p = __expf(sacc[mi][ni][j] - mn);
                    sacc[mi][ni][j] = p;
                    ps += p;
                }
                ps += __shfl_xor(ps, 1);
                ps += __shfl_xor(ps, 2);
                ps += __shfl_xor(ps, 4);
                ps += __shfl_xor(ps, 8);
                l_st[mi][j] = l_st[mi][j] * sc + ps;
                #pragma unroll
                for (int di = 0; di < 4; di++) oacc[mi][di][j] *= sc;
            }
        }
        #pragma unroll
        for (int mi = 0; mi < 4; mi++)
            #pragma unroll
            for (int ni = 0; ni < 4; ni++)
                #pragma unroll
                for (int j = 0; j < 4; j++)
                    Pl[wid][mi*16 + (lg<<2) + j][ni*16 + lr] = (_Float16)sacc[mi][ni][j];
        #pragma unroll
        for (int kk = 0; kk < 2; kk++) {
            h8 pf[4], vf[4];
            #pragma unroll
            for (int mi = 0; mi < 4; mi++)
                pf[mi] = *(const h8*)&Pl[wid][mi*16 + lr][kk*32 + lk];
            #pragma unroll
            for (int di = 0; di < 4; di++)
                vf[di] = *(const h8*)&Vt[di*16 + lr][kk*32 + lk];
            #pragma unroll
            for (int mi = 0; mi < 4; mi++)
                #pragma unroll
                for (int di = 0; di < 4; di++)
                    oacc[mi][di] = __builtin_amdgcn_mfma_f32_16x16x32_f16(pf[mi], vf[di], oacc[mi][di], 0, 0, 0);
        }
    }
    _Float16* obase = o + (size_t)b * 256 + head * 64;
    #pragma unroll
    for (int mi = 0; mi < 4; mi++) {
        #pragma unroll
        for (int j = 0; j < 4; j++) {
            const float inv = 1.f / l_st[mi][j];
            const size_t rowoff = (size_t)(q0 + mi*16 + (lg<<2) + j) * 65536;
            #pragma unroll
            for (int di = 0; di < 4; di++)
                obase[rowoff + di*16 + lr] = (_Float16)(oacc[mi][di][j] * inv);
        }
    }
}

// ---------- LayerNorm; optional fp16-plane addin; f32 or fp16(/plane) out ----------
template<int OPL, typename OT>
__global__ __launch_bounds__(256) void ln_kernel(const float* __restrict__ x,
    const float* __restrict__ g, const float* __restrict__ bt,
    const _Float16* __restrict__ addin, const _Float16* __restrict__ addinLo,
    OT* __restrict__ out, long oplane, int nrows)
{
    const int gid = blockIdx.x * 256 + threadIdx.x;
    const int row = gid >> 6;
    const int lane = threadIdx.x & 63;
    if (row >= nrows) return;
    const float* xr = x + (size_t)row * 256;
    float4 v = *(const float4*)(xr + (lane<<2));
    float s = v.x + v.y + v.z + v.w;
    #pragma unroll
    for (int off = 32; off > 0; off >>= 1) s += __shfl_xor(s, off, 64);
    const float mean = s * (1.0f/256.0f);
    const float dx = v.x-mean, dy = v.y-mean, dz = v.z-mean, dw = v.w-mean;
    float ss = dx*dx + dy*dy + dz*dz + dw*dw;
    #pragma unroll
    for (int off = 32; off > 0; off >>= 1) ss += __shfl_xor(ss, off, 64);
    const float inv = rsqrtf(ss * (1.0f/256.0f) + 1e-5f);
    const float4 gv = *(const float4*)(g + (lane<<2));
    const float4 bv = *(const float4*)(bt + (lane<<2));
    float ov[4];
    ov[0] = dx*inv*gv.x + bv.x;
    ov[1] = dy*inv*gv.y + bv.y;
    ov[2] = dz*inv*gv.z + bv.z;
    ov[3] = dw*inv*gv.w + bv.w;
    const size_t base = (size_t)row*256 + (lane<<2);
    if (addin) {
        #pragma unroll
        for (int j = 0; j < 4; j++) {
            ov[j] += (float)addin[base+j];
            if (addinLo) ov[j] += (float)addinLo[base+j];
        }
    }
    #pragma unroll
    for (int j = 0; j < 4; j++) {
        if (OPL) {
            _Float16 hh = (_Float16)ov[j];
            ((_Float16*)out)[base+j] = hh;
            ((_Float16*)out)[base+j+oplane] = (_Float16)(ov[j] - (float)hh);
        } else if (sizeof(OT) == 2) {
            ((_Float16*)out)[base+j] = (_Float16)ov[j];
        } else {
            ((float*)out)[base+j] = ov[j];
        }
    }
}

// ---------- masked softmax over i for e[b][t][i], in place, fp32 ----------
__global__ __launch_bounds__(256) void smax_kernel(float* __restrict__ e,
                                                   const int* __restrict__ seqlen)
{
    const int gid = blockIdx.x * 256 + threadIdx.x;
    const int row = gid >> 6;               // row = b*256 + t
    const int lane = threadIdx.x & 63;
    const int L = seqlen[row >> 8];
    float* er = e + (size_t)row * 256;
    float4 v = *(const float4*)(er + (lane<<2));
    const int i0 = lane << 2;
    const float x0 = (i0+0 < L) ? v.x : -1e30f;
    const float x1 = (i0+1 < L) ? v.y : -1e30f;
    const float x2 = (i0+2 < L) ? v.z : -1e30f;
    const float x3 = (i0+3 < L) ? v.w : -1e30f;
    float mx = fmaxf(fmaxf(x0,x1), fmaxf(x2,x3));
    #pragma unroll
    for (int off = 32; off > 0; off >>= 1) mx = fmaxf(mx, __shfl_xor(mx, off, 64));
    const float p0 = (i0+0 < L) ? __expf(x0-mx) : 0.f;
    const float p1 = (i0+1 < L) ? __expf(x1-mx) : 0.f;
    const float p2 = (i0+2 < L) ? __expf(x2-mx) : 0.f;
    const float p3 = (i0+3 < L) ? __expf(x3-mx) : 0.f;
    float s = p0+p1+p2+p3;
    #pragma unroll
    for (int off = 32; off > 0; off >>= 1) s += __shfl_xor(s, off, 64);
    const float inv = 1.f / s;
    v.x = p0*inv; v.y = p1*inv; v.z = p2*inv; v.w = p3*inv;
    *(float4*)(er + (lane<<2)) = v;
}

// ---------- head: logits (512->7) + log_softmax + ragged scatter; hid fp16 ----------
__global__ __launch_bounds__(256) void head_kernel(const _Float16* __restrict__ hidden,
    const float* __restrict__ Wsm, const float* __restrict__ bsm,
    const int* __restrict__ seqlen, const int* __restrict__ offs,
    float* __restrict__ out)
{
    const int gid = blockIdx.x * 256 + threadIdx.x;
    const int row = gid >> 6;
    const int lane = threadIdx.x & 63;
    if (row >= MTB) return;
    const int t = row >> 8, b = row & 255;
    if (t >= seqlen[b]) return;
    const _Float16* hr = hidden + (size_t)row * 512;
    const h8 hu = *(const h8*)(hr + lane*8);
    float hv[8];
    #pragma unroll
    for (int j = 0; j < 8; j++) hv[j] = (float)hu[j];
    float lg[7];
    #pragma unroll
    for (int c = 0; c < 7; c++) {
        const float* wr = Wsm + c*512 + lane*8;
        const float4 w0 = *(const float4*)wr;
        const float4 w1 = *(const float4*)(wr + 4);
        float acc = hv[0]*w0.x + hv[1]*w0.y + hv[2]*w0.z + hv[3]*w0.w
                  + hv[4]*w1.x + hv[5]*w1.y + hv[6]*w1.z + hv[7]*w1.w;
        #pragma unroll
        for (int off = 32; off > 0; off >>= 1) acc += __shfl_xor(acc, off, 64);
        lg[c] = acc + bsm[c];
    }
    float mx = lg[0];
    #pragma unroll
    for (int c = 1; c < 7; c++) mx = fmaxf(mx, lg[c]);
    float s = 0.f;
    #pragma unroll
    for (int c = 0; c < 7; c++) s += __expf(lg[c] - mx);
    const float lse = mx + logf(s);
    if (lane == 0) {
        float* orow = out + (size_t)(offs[b] + t) * 7;
        #pragma unroll
        for (int c = 0; c < 7; c++) orow[c] = lg[c] - lse;
    }
}

// ---------- positional encoding over the BATCH dim (faithful quirk) ----------
__global__ void pe_kernel(float* __restrict__ pe)
{
    const int idx = blockIdx.x * 256 + threadIdx.x;   // 65536 = 256x256
    const int b = idx >> 8, f = idx & 255;
    const int j = f >> 1;
    const float div = expf(-9.210340371976184f * (2.0f * j) * (1.0f/256.0f));
    const float arg = (float)b * div;
    pe[idx] = (f & 1) ? cosf(arg) : sinf(arg);
}

// ---------- exclusive prefix sum of seq lengths ----------
__global__ void prefix_kernel(const int* __restrict__ L, int* __restrict__ offs)
{
    if (threadIdx.x == 0) {
        int acc = 0;
        for (int i = 0; i < 256; i++) { offs[i] = acc; acc += L[i]; }
        offs[256] = acc;
    }
}

// ---------- diagnostic: report ws_size via absmax if insufficient ----------
__global__ void sentinel_kernel(float* __restrict__ out, float v)
{
    if (threadIdx.x == 0) out[0] = v;
}

// ---------------------------------------------------------------------------
extern "C" void kernel_launch(void* const* d_in, const int* in_sizes, int n_in,
                              void* d_out, int out_size, void* d_ws, size_t ws_size,
                              hipStream_t stream)
{
    const float* U_s   = (const float*)d_in[0];
    const float* U_p   = (const float*)d_in[1];
    const float* W_emb = (const float*)d_in[2];
    const float* b_emb = (const float*)d_in[3];
    const float* Wqkv  = (const float*)d_in[4];
    const float* bqkv  = (const float*)d_in[5];
    const float* Wo    = (const float*)d_in[6];
    const float* bo    = (const float*)d_in[7];
    const float* ln1_g = (const float*)d_in[8];
    const float* ln1_b = (const float*)d_in[9];
    const float* W1    = (const float*)d_in[10];
    const float* b1    = (const float*)d_in[11];
    const float* W2    = (const float*)d_in[12];
    const float* b2    = (const float*)d_in[13];
    const float* ln2_g = (const float*)d_in[14];
    const float* ln2_b = (const float*)d_in[15];
    const float* W_fc  = (const float*)d_in[16];
    const float* b_fc  = (const float*)d_in[17];
    const float* W_sm  = (const float*)d_in[18];
    const float* b_sm  = (const float*)d_in[19];
    const int*   seqlen= (const int*)d_in[20];
    float* out = (float*)d_out;

    // ---- aliased workspace arena, peak 193 MiB ----
    const size_t MiB = 1024*1024;
    const size_t KiB = 1024;
    char* ws = (char*)d_ws;
    if (ws_size < 193*MiB) {
        sentinel_kernel<<<dim3(1), dim3(64), 0, stream>>>(out, -(float)(ws_size / MiB));
        return;
    }
    const long PL = 16*1024*1024;                        // plane stride (elems)
    _Float16* h_hi = (_Float16*)(ws);                    // [0,32M)
    _Float16* h_lo = (_Float16*)(ws + 32*MiB);           // [32,64M)
    int*      offs = (int*)(ws + 64*MiB);                // 4 KiB
    char*     slot = ws + 64*MiB + 8*KiB;                // <1 MiB weight slot
    _Float16* qkv  = (_Float16*)(ws + 65*MiB);           // [65,161M), dead after attn
    _Float16* o    = (_Float16*)(ws + 161*MiB);          // [161,193M), dead after proj
    float*    res1 = (float*)(ws + 65*MiB);              // [65,129M) f32 (over dead qkv)
    float*    res2 = res1;
    _Float16* h1   = (_Float16*)(ws + 161*MiB);          // [161,193M) (over dead o)
    _Float16* w1p  = (_Float16*)(ws + 129*MiB);          // [129,130M) FF weights (fp16)
    _Float16* w2p  = (_Float16*)(ws + 130*MiB);          // [130,131M)
    _Float16* q_hi = (_Float16*)(ws + 129*MiB);          // [129,161M) (over dead w1p/w2p)
    _Float16* q_lo = (_Float16*)(ws + 161*MiB);          // [161,193M) (over dead h1)
    float*    e    = (float*)(ws + 65*MiB);              // [65,129M)  (over dead res2)
    _Float16* r    = (_Float16*)(ws);                    // [0,32M)    (over dead h planes)
    _Float16* hid  = (_Float16*)(ws + 129*MiB);          // [129,193M) (over dead q planes)

    prefix_kernel<<<dim3(1), dim3(64), 0, stream>>>(seqlen, offs);

    _Float16* wp  = (_Float16*)slot;                     // rotating weight plane
    float*    pe  = (float*)(slot + 512*KiB);            // 256 KiB, embed only

    // --- embed: h(planes) = mask(U_s) @ W_emb^T + b_emb + pe[b,:] ---
    cvt_kernel<<<dim3(256), 256, 0, stream>>>(W_emb, 256, 8, wp, 65536);
    pe_kernel<<<dim3(256), dim3(256), 0, stream>>>(pe);
    gemm_h<E_BIAS|E_PE|E_MASKA, 0, 2, _Float16, 1, float, 0, 1>
        <<<dim3(2,512,1), 256, 0, stream>>>(
        MTB,256,256, U_s,nullptr,256,0, wp,256,0, h_hi,PL,256,0,
        b_emb, (const float*)nullptr, nullptr, pe, seqlen);

    // --- qkv = h @ Wqkv^T + bqkv (fp16) ---
    cvt_kernel<<<dim3(768), 256, 0, stream>>>(Wqkv, 256, 8, wp, 196608);
    gemm_h<E_BIAS, 2, 2, _Float16, 0, float, 0, 1>
        <<<dim3(6,512,1), 256, 0, stream>>>(
        MTB,768,256, h_hi,nullptr,256,0, wp,256,0, qkv,0,768,0,
        bqkv, (const float*)nullptr, nullptr, nullptr, nullptr);

    // --- MFMA flash attention -> o [T,B,256] fp16 ---
    attn_kernel<<<dim3(256,4), 256, 0, stream>>>(qkv, o);

    // --- res1 = o @ Wo^T + bo + h(planes) ---
    cvt_kernel<<<dim3(256), 256, 0, stream>>>(Wo, 256, 8, wp, 65536);
    gemm_h<E_BIAS|E_RES, 2, 2, float, 0, _Float16, 1, 1>
        <<<dim3(2,512,1), 256, 0, stream>>>(
        MTB,256,256, o,nullptr,256,0, wp,256,0, res1,0,256,0,
        bo, h_hi, h_lo, nullptr, nullptr);

    // --- h1 = LN1(res1) (fp16) ---
    ln_kernel<0, _Float16><<<dim3(MTB/4), 256, 0, stream>>>(
        res1, ln1_g, ln1_b, nullptr, nullptr, h1, 0, MTB);

    // --- fused FF v5: res2 = h1 + relu(h1@W1^T+b1)@W2^T + b2 ---
    cvt_kernel<<<dim3(2048), 256, 0, stream>>>(W1, 256, 8, w1p, 524288);
    cvt_kernel<<<dim3(2048), 256, 0, stream>>>(W2, 2048, 11, w2p, 524288);
    ff_kernel<<<dim3(1024), 256, 0, stream>>>(h1, w1p, w2p, b1, b2, res2);

    // --- q(planes) = h(planes) + LN2(res2) ---
    ln_kernel<1, _Float16><<<dim3(MTB/4), 256, 0, stream>>>(
        res2, ln2_g, ln2_b, h_hi, h_lo, q_hi, PL, MTB);

    // --- e[b][t][i] = q . U_p  (3-pass split-fp16, fp32-class) ---
    gemm_h<0, 3, 0, float, 0, float, 0, 0>
        <<<dim3(2,2,256), 256, 0, stream>>>(
        256,256,256, q_hi,q_lo,65536,256, U_p,65536,256, e,0,256,65536,
        nullptr, (const float*)nullptr, nullptr, nullptr, nullptr);

    // --- masked softmax over i ---
    smax_kernel<<<dim3(MTB/4), 256, 0, stream>>>(e, seqlen);

    // --- r = a @ U_p (fp16 out) ---
    gemm_h<0, 0, 1, _Float16, 0, float, 0, 0>
        <<<dim3(2,2,256), 256, 0, stream>>>(
        256,256,256, e,nullptr,256,65536, U_p,65536,256, r,0,65536,256,
        nullptr, (const float*)nullptr, nullptr, nullptr, nullptr);

    // --- hidden = relu([mask(U_s), r] @ W_fc^T + b_fc) fp16, fused K=512 ---
    cvt_kernel<<<dim3(1024), 256, 0, stream>>>(W_fc, 512, 9, wp, 262144);
    gemm_h<E_BIAS|E_RELU|E_MASKA, 4, 2, _Float16, 0, float, 0, 1>
        <<<dim3(4,512,1), 256, 0, stream>>>(
        MTB,512,512, U_s,r,256,0, wp,512,0, hid,0,512,0,
        b_fc, (const float*)nullptr, nullptr, nullptr, seqlen);

    // --- logits + log_softmax + ragged gather ---
    head_kernel<<<dim3(MTB/4), 256, 0, stream>>>(hid, W_sm, b_sm, seqlen, offs, out);
}

// Round 15
// 901.838 us; speedup vs baseline: 1.3833x; 1.0245x over previous
//
#include <hip/hip_runtime.h>

#define MTB 65536   // T*B rows

typedef unsigned int uint;
typedef unsigned short ushort;

typedef _Float16 h8 __attribute__((ext_vector_type(8)));   // 8 fp16 (4 VGPR)
typedef __attribute__((ext_vector_type(4))) float f4;      // mfma accumulator

enum { E_BIAS=1, E_RELU=2, E_ACC=4, E_RES=8, E_PE=16, E_MASKA=32 };

__device__ __forceinline__ float ldsc(const float* p) { return *p; }
__device__ __forceinline__ float ldsc(const _Float16* p) { return (float)*p; }

__device__ __forceinline__ h8 uint4_to_h8(uint4 u) { return __builtin_bit_cast(h8, u); }

// ---------------------------------------------------------------------------
// fp16 MFMA GEMM: C = A @ W^T (+epilogue), 128x128 tile, BK=32.
// AMODE: 0 f32->fp16 staging (MASKA ok); 2 fp16 copy; 3 fp16 2-plane 3-pass;
//        4 hybrid K=512 (f32 masked k<256, fp16 k>=256)
// BMODE: 0 f32 [N,K] -> split 2 planes; 1 f32 [K,N] transpose+cvt;
//        2 fp16 [N,K] copy; 3 f32 [N,K] -> single fp16 (no split)
// SWZ=1: XCD-aware bijective block remap (nwg%8==0, gridDim.z==1).
// ---------------------------------------------------------------------------
template<int EPI, int AMODE, int BMODE, typename CT, int CPL, typename RT, int RPL, int SWZ>
__global__ __launch_bounds__(256) void gemm_h(
    int M, int N, int K,
    const void* __restrict__ Ap, const void* __restrict__ Ap2, int lda, long batchA,
    const void* __restrict__ Bp, int ldw, long batchW,
    CT* __restrict__ C, long cplane, int ldc, long batchC,
    const float* __restrict__ bias,
    const RT* __restrict__ res, const RT* __restrict__ resLo,
    const float* __restrict__ pe,
    const int* __restrict__ seqlen)
{
    __shared__ _Float16 Ah[128][40];
    __shared__ _Float16 Al[(AMODE==3)?128:1][40];
    __shared__ _Float16 Bh[128][40];
    __shared__ _Float16 Bl[(BMODE==0)?128:1][40];

    const int z = blockIdx.z;
    C += (size_t)z * batchC;
    const float*    Af  = (const float*)Ap + (AMODE==0 ? (size_t)z*batchA : 0);
    const _Float16* Ahp = (const _Float16*)Ap + ((AMODE==2||AMODE==3) ? (size_t)z*batchA : 0);
    const _Float16* Alp = (const _Float16*)Ap2 + (AMODE==3 ? (size_t)z*batchA : 0);
    const float*    Bf  = (const float*)Bp + (BMODE!=2 ? (size_t)z*batchW : 0);
    const _Float16* Bhp = (const _Float16*)Bp;

    int bx = blockIdx.x, by = blockIdx.y;
    if (SWZ) {
        const int gx = gridDim.x;
        const int nwg = gx * gridDim.y;
        const int per = nwg >> 3;
        const int id = by * gx + bx;
        const int nid = (id & 7) * per + (id >> 3);
        bx = nid % gx; by = nid / gx;
    }
    const int m0 = by * 128, n0 = bx * 128;
    const int tid = threadIdx.x;
    const int lane = tid & 63, wid = tid >> 6;
    const int wr = wid >> 1, wc = wid & 1;

    f4 acc[4][4];
    {
        f4 zr = {0.f, 0.f, 0.f, 0.f};
        #pragma unroll
        for (int i = 0; i < 4; i++)
            #pragma unroll
            for (int j = 0; j < 4; j++) acc[i][j] = zr;
    }

    for (int k0 = 0; k0 < K; k0 += 32) {
        __syncthreads();
        // ---- stage A ----
        if (AMODE == 0 || (AMODE == 4 && k0 < 256)) {
            #pragma unroll
            for (int i = 0; i < 4; i++) {
                const int row = i*32 + (tid>>3);
                const int cg  = (tid&7)<<2;
                const int m = m0 + row;
                float4 v; v.x=0.f; v.y=0.f; v.z=0.f; v.w=0.f;
                bool ok = true;
                if (EPI & E_MASKA) ok = ((m>>8) < seqlen[m&255]);
                if (ok) v = *(const float4*)(Af + (size_t)m*lda + k0 + cg);
                Ah[row][cg+0] = (_Float16)v.x;
                Ah[row][cg+1] = (_Float16)v.y;
                Ah[row][cg+2] = (_Float16)v.z;
                Ah[row][cg+3] = (_Float16)v.w;
            }
        } else if (AMODE == 4) {
            const _Float16* Ar = (const _Float16*)Ap2;
            const int row = tid >> 1;
            const int cg  = (tid & 1) << 4;
            const size_t off = (size_t)(m0 + row) * 256 + (k0 - 256) + cg;
            *(uint4*)&Ah[row][cg]     = *(const uint4*)(Ar + off);
            *(uint4*)&Ah[row][cg + 8] = *(const uint4*)(Ar + off + 8);
        } else {
            const int row = tid >> 1;
            const int cg  = (tid & 1) << 4;
            const size_t off = (size_t)(m0 + row) * lda + k0 + cg;
            *(uint4*)&Ah[row][cg]     = *(const uint4*)(Ahp + off);
            *(uint4*)&Ah[row][cg + 8] = *(const uint4*)(Ahp + off + 8);
            if (AMODE == 3) {
                *(uint4*)&Al[row][cg]     = *(const uint4*)(Alp + off);
                *(uint4*)&Al[row][cg + 8] = *(const uint4*)(Alp + off + 8);
            }
        }
        // ---- stage B ----
        if (BMODE == 2) {
            const int row = tid >> 1;
            const int cg  = (tid & 1) << 4;
            const size_t off = (size_t)(n0 + row) * ldw + k0 + cg;
            *(uint4*)&Bh[row][cg]     = *(const uint4*)(Bhp + off);
            *(uint4*)&Bh[row][cg + 8] = *(const uint4*)(Bhp + off + 8);
        } else if (BMODE == 0) {
            #pragma unroll
            for (int i = 0; i < 4; i++) {
                const int row = i*32 + (tid>>3);
                const int cg  = (tid&7)<<2;
                float4 v = *(const float4*)(Bf + (size_t)(n0+row)*ldw + k0 + cg);
                _Float16 h0 = (_Float16)v.x, h1 = (_Float16)v.y,
                         h2 = (_Float16)v.z, h3 = (_Float16)v.w;
                Bh[row][cg+0]=h0; Bl[row][cg+0]=(_Float16)(v.x-(float)h0);
                Bh[row][cg+1]=h1; Bl[row][cg+1]=(_Float16)(v.y-(float)h1);
                Bh[row][cg+2]=h2; Bl[row][cg+2]=(_Float16)(v.z-(float)h2);
                Bh[row][cg+3]=h3; Bl[row][cg+3]=(_Float16)(v.w-(float)h3);
            }
        } else if (BMODE == 3) {
            #pragma unroll
            for (int i = 0; i < 4; i++) {
                const int row = i*32 + (tid>>3);
                const int cg  = (tid&7)<<2;
                float4 v = *(const float4*)(Bf + (size_t)(n0+row)*ldw + k0 + cg);
                Bh[row][cg+0]=(_Float16)v.x; Bh[row][cg+1]=(_Float16)v.y;
                Bh[row][cg+2]=(_Float16)v.z; Bh[row][cg+3]=(_Float16)v.w;
            }
        } else {  // BMODE == 1 : W f32 [K,N], transpose + cvt
            #pragma unroll
            for (int i = 0; i < 4; i++) {
                const int kr = i*8 + (tid>>5);
                const int ng = (tid&31)<<2;
                float4 v = *(const float4*)(Bf + (size_t)(k0+kr)*ldw + n0 + ng);
                Bh[ng+0][kr] = (_Float16)v.x;
                Bh[ng+1][kr] = (_Float16)v.y;
                Bh[ng+2][kr] = (_Float16)v.z;
                Bh[ng+3][kr] = (_Float16)v.w;
            }
        }
        __syncthreads();
        // ---- fragments + MFMA ----
        const int lr = lane & 15, lk = (lane>>4)<<3;
        h8 ah[4], bh[4];
        #pragma unroll
        for (int i = 0; i < 4; i++) {
            ah[i] = *(const h8*)&Ah[wr*64 + i*16 + lr][lk];
            bh[i] = *(const h8*)&Bh[wc*64 + i*16 + lr][lk];
        }
        #pragma unroll
        for (int mi = 0; mi < 4; mi++)
            #pragma unroll
            for (int ni = 0; ni < 4; ni++)
                acc[mi][ni] = __builtin_amdgcn_mfma_f32_16x16x32_f16(ah[mi], bh[ni], acc[mi][ni], 0, 0, 0);
        if (AMODE == 3) {
            h8 al[4], bl[4];
            #pragma unroll
            for (int i = 0; i < 4; i++) {
                al[i] = *(const h8*)&Al[wr*64 + i*16 + lr][lk];
                bl[i] = *(const h8*)&Bl[wc*64 + i*16 + lr][lk];
            }
            #pragma unroll
            for (int mi = 0; mi < 4; mi++)
                #pragma unroll
                for (int ni = 0; ni < 4; ni++) {
                    acc[mi][ni] = __builtin_amdgcn_mfma_f32_16x16x32_f16(ah[mi], bl[ni], acc[mi][ni], 0, 0, 0);
                    acc[mi][ni] = __builtin_amdgcn_mfma_f32_16x16x32_f16(al[mi], bh[ni], acc[mi][ni], 0, 0, 0);
                }
        }
    }
    // ---- epilogue: C row = 4*(lane>>4)+reg, col = lane&15 ----
    const int colb = n0 + wc*64;
    const int rowb = m0 + wr*64;
    #pragma unroll
    for (int ni = 0; ni < 4; ni++) {
        const int col = colb + ni*16 + (lane & 15);
        float bv = (EPI & E_BIAS) ? bias[col] : 0.f;
        #pragma unroll
        for (int mi = 0; mi < 4; mi++) {
            const int r0 = rowb + mi*16 + ((lane>>4)<<2);
            #pragma unroll
            for (int j = 0; j < 4; j++) {
                const int row = r0 + j;
                const size_t idx = (size_t)row*ldc + col;
                float v = acc[mi][ni][j] + bv;
                if (EPI & E_PE)  v += pe[((row & 255) << 8) + col];
                if (EPI & E_RES) {
                    v += ldsc(res + idx);
                    if (RPL) v += ldsc(resLo + idx);
                }
                CT* cp = C + idx;
                if (EPI & E_ACC) v += ldsc((const CT*)cp);
                if (EPI & E_RELU) v = fmaxf(v, 0.f);
                if (CPL) {
                    _Float16 hh = (_Float16)v;
                    *(_Float16*)cp = hh;
                    *((_Float16*)cp + cplane) = (_Float16)(v - (float)hh);
                } else if (sizeof(CT) == 2) {
                    *(_Float16*)cp = (_Float16)v;
                } else {
                    *(float*)cp = v;
                }
            }
        }
    }
}

// ---------------------------------------------------------------------------
// Fused FF v5 (round-12 proven): zt LDS, all-16x16x32, T14 rolling prefetch,
// 36-stride Bs, register A-fragments. 64 h-rows per block.
// ---------------------------------------------------------------------------
__global__ __launch_bounds__(256) void ff_kernel(
    const _Float16* __restrict__ h1,    // [65536][256] fp16
    const _Float16* __restrict__ W1p,   // [2048][256] fp16
    const _Float16* __restrict__ W2p,   // [256][2048] fp16
    const float* __restrict__ b1,
    const float* __restrict__ b2,
    float* __restrict__ res2)           // [65536][256] f32
{
    __shared__ _Float16 Bs[256][36];    // 18.4 KB
    __shared__ _Float16 zt[64][136];    // 17.4 KB
    const int m0 = blockIdx.x * 64;
    const int tid = threadIdx.x;
    const int lane = tid & 63, wid = tid >> 6;
    const int wr = wid >> 1, wc = wid & 1;
    const int lr = lane & 15, lg = lane >> 4;
    const int lk = lg << 3;
    const int l4 = lg << 2;
    const int srow = tid >> 1, sh = tid & 1;   // W1 staging mapping

    h8 af[2][8];
    #pragma unroll
    for (int mi = 0; mi < 2; mi++)
        #pragma unroll
        for (int ks = 0; ks < 8; ks++)
            af[mi][ks] = *(const h8*)(h1 + (size_t)(m0 + wr*32 + mi*16 + lr) * 256 + ks*32 + lk);

    f4 acc2[2][8];
    {
        f4 zr = {0.f,0.f,0.f,0.f};
        #pragma unroll
        for (int mi = 0; mi < 2; mi++)
            #pragma unroll
            for (int ni = 0; ni < 8; ni++) acc2[mi][ni] = zr;
    }

    uint4 p1a, p1b;      // W1 piece: 16 fp16/thread
    uint4 p2[4];         // W2 piece: 32 fp16/thread
    {
        const _Float16* g = W1p + (size_t)srow * 256 + sh*16;   // c=0, ks=0
        p1a = *(const uint4*)g; p1b = *(const uint4*)(g + 8);
    }

    for (int c = 0; c < 16; c++) {
        f4 acc1[2][4];
        {
            f4 zr = {0.f,0.f,0.f,0.f};
            #pragma unroll
            for (int mi = 0; mi < 2; mi++)
                #pragma unroll
                for (int ni = 0; ni < 4; ni++) acc1[mi][ni] = zr;
        }
        for (int ks = 0; ks < 8; ks++) {
            __syncthreads();
            {
                _Float16* d = &Bs[srow][sh*16];
                uint2 t0; t0.x=p1a.x; t0.y=p1a.y; *(uint2*)(d+0)  = t0;
                uint2 t1; t1.x=p1a.z; t1.y=p1a.w; *(uint2*)(d+4)  = t1;
                uint2 t2; t2.x=p1b.x; t2.y=p1b.y; *(uint2*)(d+8)  = t2;
                uint2 t3; t3.x=p1b.z; t3.y=p1b.w; *(uint2*)(d+12) = t3;
            }
            __syncthreads();
            if (ks < 7) {
                const _Float16* g = W1p + (size_t)(c*128 + srow) * 256 + (ks+1)*32 + sh*16;
                p1a = *(const uint4*)g; p1b = *(const uint4*)(g + 8);
            } else {
                const _Float16* g = W2p + (size_t)tid * 2048 + c*128;
                #pragma unroll
                for (int q = 0; q < 4; q++) p2[q] = *(const uint4*)(g + 8*q);
            }
            #pragma unroll
            for (int ni = 0; ni < 4; ni++) {
                const _Float16* s = &Bs[wc*64 + ni*16 + lr][lk];
                uint2 q0 = *(const uint2*)s;
                uint2 q1 = *(const uint2*)(s + 4);
                uint4 u; u.x=q0.x; u.y=q0.y; u.z=q1.x; u.w=q1.y;
                const h8 b = uint4_to_h8(u);
                acc1[0][ni] = __builtin_amdgcn_mfma_f32_16x16x32_f16(af[0][ks], b, acc1[0][ni], 0, 0, 0);
                acc1[1][ni] = __builtin_amdgcn_mfma_f32_16x16x32_f16(af[1][ks], b, acc1[1][ni], 0, 0, 0);
            }
        }
        #pragma unroll
        for (int ni = 0; ni < 4; ni++) {
            const float bv = b1[c*128 + wc*64 + ni*16 + lr];
            #pragma unroll
            for (int mi = 0; mi < 2; mi++)
                #pragma unroll
                for (int j = 0; j < 4; j++) {
                    float v = acc1[mi][ni][j] + bv;
                    v = fmaxf(v, 0.f);
                    zt[wr*32 + mi*16 + l4 + j][wc*64 + ni*16 + lr] = (_Float16)v;
                }
        }
        __syncthreads();
        for (int kk = 0; kk < 4; kk++) {
            if (kk) __syncthreads();
            {
                _Float16* d = &Bs[tid][0];
                #pragma unroll
                for (int q = 0; q < 4; q++) {
                    uint2 ta; ta.x=p2[q].x; ta.y=p2[q].y; *(uint2*)(d + 8*q)     = ta;
                    uint2 tb; tb.x=p2[q].z; tb.y=p2[q].w; *(uint2*)(d + 8*q + 4) = tb;
                }
            }
            __syncthreads();
            if (kk < 3) {
                const _Float16* g = W2p + (size_t)tid * 2048 + c*128 + (kk+1)*32;
                #pragma unroll
                for (int q = 0; q < 4; q++) p2[q] = *(const uint4*)(g + 8*q);
            } else if (c < 15) {
                const _Float16* g = W1p + (size_t)((c+1)*128 + srow) * 256 + sh*16;
                p1a = *(const uint4*)g; p1b = *(const uint4*)(g + 8);
            }
            const h8 a0 = *(const h8*)&zt[wr*32 +      lr][kk*32 + lk];
            const h8 a1 = *(const h8*)&zt[wr*32 + 16 + lr][kk*32 + lk];
            #pragma unroll
            for (int ni = 0; ni < 8; ni++) {
                const _Float16* s = &Bs[wc*128 + ni*16 + lr][lk];
                uint2 q0 = *(const uint2*)s;
                uint2 q1 = *(const uint2*)(s + 4);
                uint4 u; u.x=q0.x; u.y=q0.y; u.z=q1.x; u.w=q1.y;
                const h8 b = uint4_to_h8(u);
                acc2[0][ni] = __builtin_amdgcn_mfma_f32_16x16x32_f16(a0, b, acc2[0][ni], 0, 0, 0);
                acc2[1][ni] = __builtin_amdgcn_mfma_f32_16x16x32_f16(a1, b, acc2[1][ni], 0, 0, 0);
            }
        }
    }
    #pragma unroll
    for (int ni = 0; ni < 8; ni++) {
        const int col = wc*128 + ni*16 + lr;
        const float bv = b2[col];
        #pragma unroll
        for (int mi = 0; mi < 2; mi++) {
            const int rl = wr*32 + mi*16 + l4;
            #pragma unroll
            for (int j = 0; j < 4; j++) {
                const size_t idx = (size_t)(m0 + rl + j) * 256 + col;
                res2[idx] = acc2[mi][ni][j] + bv + (float)h1[idx];
            }
        }
    }
}

// ---------- f32 -> fp16 plane convert (strided source) ----------
__global__ void cvt_kernel(const float* __restrict__ src, int ld, int cshift,
                           _Float16* __restrict__ dst, int total)
{
    const int i = blockIdx.x * 256 + threadIdx.x;
    if (i >= total) return;
    const int r = i >> cshift, c = i & ((1 << cshift) - 1);
    dst[i] = (_Float16)src[(size_t)r * ld + c];
}

// ---------------------------------------------------------------------------
// MFMA flash attention per (b, head).  (unchanged from round 9)
// ---------------------------------------------------------------------------
__global__ __launch_bounds__(256) void attn_kernel(const _Float16* __restrict__ qkv,
                                                   _Float16* __restrict__ o)
{
    __shared__ _Float16 Kl[64][68];
    __shared__ _Float16 Vt[64][68];
    __shared__ _Float16 Pl[4][64][68];
    const int b = blockIdx.x, head = blockIdx.y;
    const _Float16* base = qkv + (size_t)b * 768 + head * 64;
    const int tid = threadIdx.x;
    const int lane = tid & 63, wid = tid >> 6;
    const int lr = lane & 15, lg = lane >> 4;
    const int lk = lg << 3;
    const int q0 = wid * 64;

    h8 qf[4][2];
    #pragma unroll
    for (int mi = 0; mi < 4; mi++)
        #pragma unroll
        for (int kk = 0; kk < 2; kk++)
            qf[mi][kk] = *(const h8*)(base + (size_t)(q0 + mi*16 + lr) * 196608 + kk*32 + lk);

    f4 oacc[4][4];
    float m_st[4][4], l_st[4][4];
    {
        f4 zr = {0.f,0.f,0.f,0.f};
        #pragma unroll
        for (int mi = 0; mi < 4; mi++)
            #pragma unroll
            for (int di = 0; di < 4; di++) oacc[mi][di] = zr;
        #pragma unroll
        for (int mi = 0; mi < 4; mi++)
            #pragma unroll
            for (int j = 0; j < 4; j++) { m_st[mi][j] = -1e30f; l_st[mi][j] = 0.f; }
    }

    for (int kt = 0; kt < 4; kt++) {
        __syncthreads();
        {
            const int row = tid >> 2, c0 = (tid & 3) << 4;
            const _Float16* rp = base + (size_t)(kt*64 + row) * 196608;
            *(uint4*)&Kl[row][c0]     = *(const uint4*)(rp + 256 + c0);
            *(uint4*)&Kl[row][c0 + 8] = *(const uint4*)(rp + 256 + c0 + 8);
            const h8 v0 = *(const h8*)(rp + 512 + c0);
            const h8 v1 = *(const h8*)(rp + 512 + c0 + 8);
            #pragma unroll
            for (int j = 0; j < 8; j++) {
                Vt[c0 + j][row]     = v0[j];
                Vt[c0 + 8 + j][row] = v1[j];
            }
        }
        __syncthreads();
        f4 sacc[4][4];
        {
            f4 zr = {0.f,0.f,0.f,0.f};
            #pragma unroll
            for (int mi = 0; mi < 4; mi++)
                #pragma unroll
                for (int ni = 0; ni < 4; ni++) sacc[mi][ni] = zr;
        }
        #pragma unroll
        for (int kk = 0; kk < 2; kk++) {
            h8 kf[4];
            #pragma unroll
            for (int ni = 0; ni < 4; ni++)
                kf[ni] = *(const h8*)&Kl[ni*16 + lr][kk*32 + lk];
            #pragma unroll
            for (int mi = 0; mi < 4; mi++)
                #pragma unroll
                for (int ni = 0; ni < 4; ni++)
                    sacc[mi][ni] = __builtin_amdgcn_mfma_f32_16x16x32_f16(qf[mi][kk], kf[ni], sacc[mi][ni], 0, 0, 0);
        }
        #pragma unroll
        for (int mi = 0; mi < 4; mi++)
            #pragma unroll
            for (int ni = 0; ni < 4; ni++)
                #pragma unroll
                for (int j = 0; j < 4; j++) sacc[mi][ni][j] *= 0.125f;
        #pragma unroll
        for (int mi = 0; mi < 4; mi++) {
            #pragma unroll
            for (int j = 0; j < 4; j++) {
                float tm = fmaxf(fmaxf(sacc[mi][0][j], sacc[mi][1][j]),
                                 fmaxf(sacc[mi][2][j], sacc[mi][3][j]));
                tm = fmaxf(tm, __shfl_xor(tm, 1));
                tm = fmaxf(tm, __shfl_xor(tm, 2));
                tm = fmaxf(tm, __shfl_xor(tm, 4));
                tm = fmaxf(tm, __shfl_xor(tm, 8));
                const float mn = fmaxf(m_st[mi][j], tm);
                const float sc = __expf(m_st[mi][j] - mn);
                m_st[mi][j] = mn;
                float ps = 0.f;
                #pragma unroll
                for (int ni = 0; ni < 4; ni++) {
                    const float p = __expf(sacc[mi][ni][j] - mn);
                    sacc[mi][ni][j] = p;
                    ps += p;
                }
                ps += __shfl_xor(ps, 1);
                ps += __shfl_xor(ps, 2);
                ps += __shfl_xor(ps, 4);
                ps += __shfl_xor(ps, 8);
                l_st[mi][j] = l_st[mi][j] * sc + ps;
                #pragma unroll
                for (int di = 0; di < 4; di++) oacc[mi][di][j] *= sc;
            }
        }
        #pragma unroll
        for (int mi = 0; mi < 4; mi++)
            #pragma unroll
            for (int ni = 0; ni < 4; ni++)
                #pragma unroll
                for (int j = 0; j < 4; j++)
                    Pl[wid][mi*16 + (lg<<2) + j][ni*16 + lr] = (_Float16)sacc[mi][ni][j];
        #pragma unroll
        for (int kk = 0; kk < 2; kk++) {
            h8 pf[4], vf[4];
            #pragma unroll
            for (int mi = 0; mi < 4; mi++)
                pf[mi] = *(const h8*)&Pl[wid][mi*16 + lr][kk*32 + lk];
            #pragma unroll
            for (int di = 0; di < 4; di++)
                vf[di] = *(const h8*)&Vt[di*16 + lr][kk*32 + lk];
            #pragma unroll
            for (int mi = 0; mi < 4; mi++)
                #pragma unroll
                for (int di = 0; di < 4; di++)
                    oacc[mi][di] = __builtin_amdgcn_mfma_f32_16x16x32_f16(pf[mi], vf[di], oacc[mi][di], 0, 0, 0);
        }
    }
    _Float16* obase = o + (size_t)b * 256 + head * 64;
    #pragma unroll
    for (int mi = 0; mi < 4; mi++) {
        #pragma unroll
        for (int j = 0; j < 4; j++) {
            const float inv = 1.f / l_st[mi][j];
            const size_t rowoff = (size_t)(q0 + mi*16 + (lg<<2) + j) * 65536;
            #pragma unroll
            for (int di = 0; di < 4; di++)
                obase[rowoff + di*16 + lr] = (_Float16)(oacc[mi][di][j] * inv);
        }
    }
}

// ---------- LayerNorm; optional fp16-plane addin; f32 or fp16(/plane) out ----------
template<int OPL, typename OT>
__global__ __launch_bounds__(256) void ln_kernel(const float* __restrict__ x,
    const float* __restrict__ g, const float* __restrict__ bt,
    const _Float16* __restrict__ addin, const _Float16* __restrict__ addinLo,
    OT* __restrict__ out, long oplane, int nrows)
{
    const int gid = blockIdx.x * 256 + threadIdx.x;
    const int row = gid >> 6;
    const int lane = threadIdx.x & 63;
    if (row >= nrows) return;
    const float* xr = x + (size_t)row * 256;
    float4 v = *(const float4*)(xr + (lane<<2));
    float s = v.x + v.y + v.z + v.w;
    #pragma unroll
    for (int off = 32; off > 0; off >>= 1) s += __shfl_xor(s, off, 64);
    const float mean = s * (1.0f/256.0f);
    const float dx = v.x-mean, dy = v.y-mean, dz = v.z-mean, dw = v.w-mean;
    float ss = dx*dx + dy*dy + dz*dz + dw*dw;
    #pragma unroll
    for (int off = 32; off > 0; off >>= 1) ss += __shfl_xor(ss, off, 64);
    const float inv = rsqrtf(ss * (1.0f/256.0f) + 1e-5f);
    const float4 gv = *(const float4*)(g + (lane<<2));
    const float4 bv = *(const float4*)(bt + (lane<<2));
    float ov[4];
    ov[0] = dx*inv*gv.x + bv.x;
    ov[1] = dy*inv*gv.y + bv.y;
    ov[2] = dz*inv*gv.z + bv.z;
    ov[3] = dw*inv*gv.w + bv.w;
    const size_t base = (size_t)row*256 + (lane<<2);
    if (addin) {
        #pragma unroll
        for (int j = 0; j < 4; j++) {
            ov[j] += (float)addin[base+j];
            if (addinLo) ov[j] += (float)addinLo[base+j];
        }
    }
    #pragma unroll
    for (int j = 0; j < 4; j++) {
        if (OPL) {
            _Float16 hh = (_Float16)ov[j];
            ((_Float16*)out)[base+j] = hh;
            ((_Float16*)out)[base+j+oplane] = (_Float16)(ov[j] - (float)hh);
        } else if (sizeof(OT) == 2) {
            ((_Float16*)out)[base+j] = (_Float16)ov[j];
        } else {
            ((float*)out)[base+j] = ov[j];
        }
    }
}

// ---------- masked softmax over i for e[b][t][i], in place, fp32 ----------
__global__ __launch_bounds__(256) void smax_kernel(float* __restrict__ e,
                                                   const int* __restrict__ seqlen)
{
    const int gid = blockIdx.x * 256 + threadIdx.x;
    const int row = gid >> 6;               // row = b*256 + t
    const int lane = threadIdx.x & 63;
    const int L = seqlen[row >> 8];
    float* er = e + (size_t)row * 256;
    float4 v = *(const float4*)(er + (lane<<2));
    const int i0 = lane << 2;
    const float x0 = (i0+0 < L) ? v.x : -1e30f;
    const float x1 = (i0+1 < L) ? v.y : -1e30f;
    const float x2 = (i0+2 < L) ? v.z : -1e30f;
    const float x3 = (i0+3 < L) ? v.w : -1e30f;
    float mx = fmaxf(fmaxf(x0,x1), fmaxf(x2,x3));
    #pragma unroll
    for (int off = 32; off > 0; off >>= 1) mx = fmaxf(mx, __shfl_xor(mx, off, 64));
    const float p0 = (i0+0 < L) ? __expf(x0-mx) : 0.f;
    const float p1 = (i0+1 < L) ? __expf(x1-mx) : 0.f;
    const float p2 = (i0+2 < L) ? __expf(x2-mx) : 0.f;
    const float p3 = (i0+3 < L) ? __expf(x3-mx) : 0.f;
    float s = p0+p1+p2+p3;
    #pragma unroll
    for (int off = 32; off > 0; off >>= 1) s += __shfl_xor(s, off, 64);
    const float inv = 1.f / s;
    v.x = p0*inv; v.y = p1*inv; v.z = p2*inv; v.w = p3*inv;
    *(float4*)(er + (lane<<2)) = v;
}

// ---------- head: logits (512->7) + log_softmax + ragged scatter; hid fp16 ----------
__global__ __launch_bounds__(256) void head_kernel(const _Float16* __restrict__ hidden,
    const float* __restrict__ Wsm, const float* __restrict__ bsm,
    const int* __restrict__ seqlen, const int* __restrict__ offs,
    float* __restrict__ out)
{
    const int gid = blockIdx.x * 256 + threadIdx.x;
    const int row = gid >> 6;
    const int lane = threadIdx.x & 63;
    if (row >= MTB) return;
    const int t = row >> 8, b = row & 255;
    if (t >= seqlen[b]) return;
    const _Float16* hr = hidden + (size_t)row * 512;
    const h8 hu = *(const h8*)(hr + lane*8);
    float hv[8];
    #pragma unroll
    for (int j = 0; j < 8; j++) hv[j] = (float)hu[j];
    float lg[7];
    #pragma unroll
    for (int c = 0; c < 7; c++) {
        const float* wr = Wsm + c*512 + lane*8;
        const float4 w0 = *(const float4*)wr;
        const float4 w1 = *(const float4*)(wr + 4);
        float acc = hv[0]*w0.x + hv[1]*w0.y + hv[2]*w0.z + hv[3]*w0.w
                  + hv[4]*w1.x + hv[5]*w1.y + hv[6]*w1.z + hv[7]*w1.w;
        #pragma unroll
        for (int off = 32; off > 0; off >>= 1) acc += __shfl_xor(acc, off, 64);
        lg[c] = acc + bsm[c];
    }
    float mx = lg[0];
    #pragma unroll
    for (int c = 1; c < 7; c++) mx = fmaxf(mx, lg[c]);
    float s = 0.f;
    #pragma unroll
    for (int c = 0; c < 7; c++) s += __expf(lg[c] - mx);
    const float lse = mx + logf(s);
    if (lane == 0) {
        float* orow = out + (size_t)(offs[b] + t) * 7;
        #pragma unroll
        for (int c = 0; c < 7; c++) orow[c] = lg[c] - lse;
    }
}

// ---------- positional encoding over the BATCH dim (faithful quirk) ----------
__global__ void pe_kernel(float* __restrict__ pe)
{
    const int idx = blockIdx.x * 256 + threadIdx.x;   // 65536 = 256x256
    const int b = idx >> 8, f = idx & 255;
    const int j = f >> 1;
    const float div = expf(-9.210340371976184f * (2.0f * j) * (1.0f/256.0f));
    const float arg = (float)b * div;
    pe[idx] = (f & 1) ? cosf(arg) : sinf(arg);
}

// ---------- exclusive prefix sum of seq lengths ----------
__global__ void prefix_kernel(const int* __restrict__ L, int* __restrict__ offs)
{
    if (threadIdx.x == 0) {
        int acc = 0;
        for (int i = 0; i < 256; i++) { offs[i] = acc; acc += L[i]; }
        offs[256] = acc;
    }
}

// ---------- diagnostic: report ws_size via absmax if insufficient ----------
__global__ void sentinel_kernel(float* __restrict__ out, float v)
{
    if (threadIdx.x == 0) out[0] = v;
}

// ---------------------------------------------------------------------------
extern "C" void kernel_launch(void* const* d_in, const int* in_sizes, int n_in,
                              void* d_out, int out_size, void* d_ws, size_t ws_size,
                              hipStream_t stream)
{
    const float* U_s   = (const float*)d_in[0];
    const float* U_p   = (const float*)d_in[1];
    const float* W_emb = (const float*)d_in[2];
    const float* b_emb = (const float*)d_in[3];
    const float* Wqkv  = (const float*)d_in[4];
    const float* bqkv  = (const float*)d_in[5];
    const float* Wo    = (const float*)d_in[6];
    const float* bo    = (const float*)d_in[7];
    const float* ln1_g = (const float*)d_in[8];
    const float* ln1_b = (const float*)d_in[9];
    const float* W1    = (const float*)d_in[10];
    const float* b1    = (const float*)d_in[11];
    const float* W2    = (const float*)d_in[12];
    const float* b2    = (const float*)d_in[13];
    const float* ln2_g = (const float*)d_in[14];
    const float* ln2_b = (const float*)d_in[15];
    const float* W_fc  = (const float*)d_in[16];
    const float* b_fc  = (const float*)d_in[17];
    const float* W_sm  = (const float*)d_in[18];
    const float* b_sm  = (const float*)d_in[19];
    const int*   seqlen= (const int*)d_in[20];
    float* out = (float*)d_out;

    // ---- aliased workspace arena, peak 193 MiB ----
    const size_t MiB = 1024*1024;
    const size_t KiB = 1024;
    char* ws = (char*)d_ws;
    if (ws_size < 193*MiB) {
        sentinel_kernel<<<dim3(1), dim3(64), 0, stream>>>(out, -(float)(ws_size / MiB));
        return;
    }
    const long PL = 16*1024*1024;                        // plane stride (elems)
    _Float16* h_hi = (_Float16*)(ws);                    // [0,32M)
    _Float16* h_lo = (_Float16*)(ws + 32*MiB);           // [32,64M)
    int*      offs = (int*)(ws + 64*MiB);                // 4 KiB
    char*     slot = ws + 64*MiB + 8*KiB;                // <1 MiB weight slot
    _Float16* qkv  = (_Float16*)(ws + 65*MiB);           // [65,161M), dead after attn
    _Float16* o    = (_Float16*)(ws + 161*MiB);          // [161,193M), dead after proj
    float*    res1 = (float*)(ws + 65*MiB);              // [65,129M) f32 (over dead qkv)
    float*    res2 = res1;
    _Float16* h1   = (_Float16*)(ws + 161*MiB);          // [161,193M) (over dead o)
    _Float16* w1p  = (_Float16*)(ws + 129*MiB);          // [129,130M) FF weights (fp16)
    _Float16* w2p  = (_Float16*)(ws + 130*MiB);          // [130,131M)
    _Float16* q_hi = (_Float16*)(ws + 129*MiB);          // [129,161M) (over dead w1p/w2p), single plane
    float*    e    = (float*)(ws + 65*MiB);              // [65,129M)  (over dead res2)
    _Float16* r    = (_Float16*)(ws);                    // [0,32M)    (over dead h planes)
    _Float16* hid  = (_Float16*)(ws + 129*MiB);          // [129,193M) (over dead q plane)

    prefix_kernel<<<dim3(1), dim3(64), 0, stream>>>(seqlen, offs);

    _Float16* wp  = (_Float16*)slot;                     // rotating weight plane
    float*    pe  = (float*)(slot + 512*KiB);            // 256 KiB, embed only

    // --- embed: h(planes) = mask(U_s) @ W_emb^T + b_emb + pe[b,:] ---
    cvt_kernel<<<dim3(256), 256, 0, stream>>>(W_emb, 256, 8, wp, 65536);
    pe_kernel<<<dim3(256), dim3(256), 0, stream>>>(pe);
    gemm_h<E_BIAS|E_PE|E_MASKA, 0, 2, _Float16, 1, float, 0, 1>
        <<<dim3(2,512,1), 256, 0, stream>>>(
        MTB,256,256, U_s,nullptr,256,0, wp,256,0, h_hi,PL,256,0,
        b_emb, (const float*)nullptr, nullptr, pe, seqlen);

    // --- qkv = h @ Wqkv^T + bqkv (fp16) ---
    cvt_kernel<<<dim3(768), 256, 0, stream>>>(Wqkv, 256, 8, wp, 196608);
    gemm_h<E_BIAS, 2, 2, _Float16, 0, float, 0, 1>
        <<<dim3(6,512,1), 256, 0, stream>>>(
        MTB,768,256, h_hi,nullptr,256,0, wp,256,0, qkv,0,768,0,
        bqkv, (const float*)nullptr, nullptr, nullptr, nullptr);

    // --- MFMA flash attention -> o [T,B,256] fp16 ---
    attn_kernel<<<dim3(256,4), 256, 0, stream>>>(qkv, o);

    // --- res1 = o @ Wo^T + bo + h(planes) ---
    cvt_kernel<<<dim3(256), 256, 0, stream>>>(Wo, 256, 8, wp, 65536);
    gemm_h<E_BIAS|E_RES, 2, 2, float, 0, _Float16, 1, 1>
        <<<dim3(2,512,1), 256, 0, stream>>>(
        MTB,256,256, o,nullptr,256,0, wp,256,0, res1,0,256,0,
        bo, h_hi, h_lo, nullptr, nullptr);

    // --- h1 = LN1(res1) (fp16) ---
    ln_kernel<0, _Float16><<<dim3(MTB/4), 256, 0, stream>>>(
        res1, ln1_g, ln1_b, nullptr, nullptr, h1, 0, MTB);

    // --- fused FF v5: res2 = h1 + relu(h1@W1^T+b1)@W2^T + b2 ---
    cvt_kernel<<<dim3(2048), 256, 0, stream>>>(W1, 256, 8, w1p, 524288);
    cvt_kernel<<<dim3(2048), 256, 0, stream>>>(W2, 2048, 11, w2p, 524288);
    ff_kernel<<<dim3(1024), 256, 0, stream>>>(h1, w1p, w2p, b1, b2, res2);

    // --- q = h(planes) + LN2(res2), single fp16 plane ---
    ln_kernel<0, _Float16><<<dim3(MTB/4), 256, 0, stream>>>(
        res2, ln2_g, ln2_b, h_hi, h_lo, q_hi, 0, MTB);

    // --- e[b][t][i] = q . U_p  (single-pass fp16) ---
    gemm_h<0, 2, 3, float, 0, float, 0, 0>
        <<<dim3(2,2,256), 256, 0, stream>>>(
        256,256,256, q_hi,nullptr,65536,256, U_p,65536,256, e,0,256,65536,
        nullptr, (const float*)nullptr, nullptr, nullptr, nullptr);

    // --- masked softmax over i ---
    smax_kernel<<<dim3(MTB/4), 256, 0, stream>>>(e, seqlen);

    // --- r = a @ U_p (fp16 out) ---
    gemm_h<0, 0, 1, _Float16, 0, float, 0, 0>
        <<<dim3(2,2,256), 256, 0, stream>>>(
        256,256,256, e,nullptr,256,65536, U_p,65536,256, r,0,65536,256,
        nullptr, (const float*)nullptr, nullptr, nullptr, nullptr);

    // --- hidden = relu([mask(U_s), r] @ W_fc^T + b_fc) fp16, fused K=512 ---
    cvt_kernel<<<dim3(1024), 256, 0, stream>>>(W_fc, 512, 9, wp, 262144);
    gemm_h<E_BIAS|E_RELU|E_MASKA, 4, 2, _Float16, 0, float, 0, 1>
        <<<dim3(4,512,1), 256, 0, stream>>>(
        MTB,512,512, U_s,r,256,0, wp,512,0, hid,0,512,0,
        b_fc, (const float*)nullptr, nullptr, nullptr, seqlen);

    // --- logits + log_softmax + ragged gather ---
    head_kernel<<<dim3(MTB/4), 256, 0, stream>>>(hid, W_sm, b_sm, seqlen, offs, out);
}